// Round 3
// baseline (341.065 us; speedup 1.0000x reference)
//
#include <hip/hip_runtime.h>
#include <math.h>

#define B_      64
#define S_      128
#define KN      16
#define EE      128
#define HH      100
#define NTREE   8192            // B_*S_

typedef __attribute__((ext_vector_type(8))) short   bf8;    // 8 bf16 (4 VGPRs)
typedef __attribute__((ext_vector_type(4))) float   f32x4;
typedef __attribute__((ext_vector_type(8))) float   f32x8;
typedef __attribute__((ext_vector_type(4))) unsigned int u32x4;

// workspace byte offsets (256-aligned)
#define EMB_BF_OFF   0u           // 50000*128*2 = 12,800,000
#define WC_BF_OFF    12800000u    // 128*128*2   = 32,768
#define WIH_BF_OFF   12832768u    // 768*128*2   = 196,608 (padded [dir][g][128j][128k])
#define WHH_BF_OFF   13029376u    // 768*128*2   = 196,608 (padded, zero pads)
#define ENC_BF_OFF   13225984u    // 16384*128*2 = 4,194,304   rows = e*8192 + t*64 + b
#define G_BF_OFF     17420288u    // 16384*768*2 = 25,165,824  [row][dir*384+g*128+j]
#define HMAX_OFF     42586112u    // 25600*4     = 102,400

__constant__ float c_cnt[16] = {16.f,8.f,7.f,4.f,3.f,3.f,3.f,2.f,
                                1.f,1.f,1.f,1.f,1.f,1.f,1.f,1.f};

__device__ __forceinline__ float bf2f(unsigned short u) {
    unsigned int x = ((unsigned int)u) << 16;
    return __builtin_bit_cast(float, x);
}
__device__ __forceinline__ unsigned short f2bf(float f) {
    unsigned int x = __builtin_bit_cast(unsigned int, f);
    x = x + 0x7fffu + ((x >> 16) & 1u);          // RNE
    return (unsigned short)(x >> 16);
}
__device__ __forceinline__ float bfq(const ushort4& v, int r) {
    unsigned short u = (r == 0) ? v.x : (r == 1) ? v.y : (r == 2) ? v.z : v.w;
    return bf2f(u);
}
// swizzle a 16B-aligned column-byte offset within a 256B row
#define SWZ(row, cb) ((cb) ^ (((row) & 7) << 4))

// ---------------------------------------------------------------------------
// K0: fp32 -> bf16 prep: emb, Wc, wih padded [2][3][128][128], whh padded same
// ---------------------------------------------------------------------------
#define NA 1600000   // emb float4s
#define NB 4096      // Wc float4s
#define NC 24576     // wih_pad ushort4s (768*128/4)
#define ND 24576     // whh_pad ushort4s
__global__ __launch_bounds__(256) void k_prep(
    const float* __restrict__ emb, const float* __restrict__ Wc,
    const float* __restrict__ wih_f, const float* __restrict__ wih_b,
    const float* __restrict__ whh_f, const float* __restrict__ whh_b,
    unsigned short* __restrict__ emb_bf, unsigned short* __restrict__ wc_bf,
    unsigned short* __restrict__ wih_pad, unsigned short* __restrict__ whh_pad)
{
    const int i = blockIdx.x * 256 + threadIdx.x;
    if (i < NA + NB) {
        const float* src = (i < NA) ? emb : Wc;
        unsigned short* dst = (i < NA) ? emb_bf : wc_bf;
        const int j = (i < NA) ? i : i - NA;
        float4 v = ((const float4*)src)[j];
        ushort4 o;
        o.x = f2bf(v.x); o.y = f2bf(v.y); o.z = f2bf(v.z); o.w = f2bf(v.w);
        ((ushort4*)dst)[j] = o;
    } else if (i < NA + NB + NC) {
        const int u = i - NA - NB;                  // 0..24575
        const int row = u >> 5, k4 = u & 31;        // row 0..767
        const int dir = row / 384, rem = row % 384, g = rem >> 7, j = rem & 127;
        ushort4 o = {0, 0, 0, 0};
        if (j < 100) {
            const float* w = dir ? wih_b : wih_f;   // [300][128]
            float4 v = ((const float4*)w)[(g * 100 + j) * 32 + k4];
            o.x = f2bf(v.x); o.y = f2bf(v.y); o.z = f2bf(v.z); o.w = f2bf(v.w);
        }
        ((ushort4*)wih_pad)[u] = o;
    } else if (i < NA + NB + NC + ND) {
        const int u = i - NA - NB - NC;
        const int row = u >> 5, k0 = (u & 31) * 4;
        const int dir = row / 384, rem = row % 384, g = rem >> 7, j = rem & 127;
        ushort4 o = {0, 0, 0, 0};
        if (j < 100) {
            const float* w = dir ? whh_b : whh_f;   // [300][100]
            const float* wr = w + (g * 100 + j) * 100;
            unsigned short t[4];
            #pragma unroll
            for (int q = 0; q < 4; ++q)
                t[q] = (k0 + q < 100) ? f2bf(wr[k0 + q]) : (unsigned short)0;
            o.x = t[0]; o.y = t[1]; o.z = t[2]; o.w = t[3];
        }
        ((ushort4*)whh_pad)[u] = o;
    }
}

// ---------------------------------------------------------------------------
// K1: gather bf16 emb -> register tree-aggregate -> bf16 A tile; B = Wc bf16.
// MFMA 16x16x32; epilogue: +cnt*bc, per-tree max over 16 nodes, relu.
// enc rows stored as e*8192 + t*64 + b (GRU-friendly order).
// ---------------------------------------------------------------------------
__global__ __launch_bounds__(512) void k_encode(
    const int* __restrict__ tok1, const int* __restrict__ tok2,
    const unsigned short* __restrict__ emb_bf,
    const unsigned short* __restrict__ wc_bf,
    const float* __restrict__ bc,
    unsigned short* __restrict__ enc_bf)
{
    __shared__ unsigned short A_lds[128 * 128];   // [row][k] swizzled
    __shared__ unsigned short B_lds[128 * 128];   // [col][k] swizzled
    const int tid = threadIdx.x;
    const int blk = blockIdx.x;
    const int e = blk >> 10;
    const int tree0 = (blk & 1023) * 8;
    const int* __restrict__ tok = e ? tok2 : tok1;

    if (tid < 128) {
        const int tr = tid >> 4, seg = tid & 15;
        const int tb = (tree0 + tr) * KN;
        int tkn[16];
        #pragma unroll
        for (int n = 0; n < 16; ++n) tkn[n] = tok[tb + n];
        f32x8 a[16];
        #pragma unroll
        for (int n = 0; n < 16; ++n) {
            bf8 v = *(const bf8*)(emb_bf + (size_t)tkn[n] * EE + seg * 8);
            f32x8 f;
            #pragma unroll
            for (int q = 0; q < 8; ++q) f[q] = bf2f((unsigned short)v[q]);
            a[n] = f;
        }
        a[7] += a[15];
        a[3] += a[7]  + a[8];   a[4] += a[9]  + a[10];
        a[5] += a[11] + a[12];  a[6] += a[13] + a[14];
        a[1] += a[3]  + a[4];   a[2] += a[5]  + a[6];
        a[0] += a[1]  + a[2];
        #pragma unroll
        for (int n = 0; n < 16; ++n) {
            const int row = tr * 16 + n;
            bf8 o;
            #pragma unroll
            for (int q = 0; q < 8; ++q) o[q] = (short)f2bf(a[n][q]);
            *(bf8*)((char*)A_lds + row * 256 + SWZ(row, seg * 16)) = o;
        }
    } else if (tid >= 256) {
        const int u0 = tid - 256;
        #pragma unroll
        for (int it = 0; it < 8; ++it) {
            const int idx = u0 + 256 * it;
            const int row = idx >> 4, seg = idx & 15;
            u32x4 v = *(const u32x4*)(wc_bf + row * EE + seg * 8);
            *(u32x4*)((char*)B_lds + row * 256 + SWZ(row, seg * 16)) = v;
        }
    }
    __syncthreads();

    const int wid = tid >> 6, lane = tid & 63;
    const int wr = wid >> 1, wc = wid & 1;
    const int l15 = lane & 15, lg = lane >> 4;

    f32x4 acc[2][4];
    #pragma unroll
    for (int rt = 0; rt < 2; ++rt)
        #pragma unroll
        for (int ct = 0; ct < 4; ++ct) acc[rt][ct] = (f32x4){0.f, 0.f, 0.f, 0.f};

    #pragma unroll
    for (int ks = 0; ks < 4; ++ks) {
        bf8 aF[2], bF[4];
        #pragma unroll
        for (int rt = 0; rt < 2; ++rt) {
            const int row = wr * 32 + rt * 16 + l15;
            aF[rt] = *(const bf8*)((const char*)A_lds + row * 256 + SWZ(row, ks * 64 + lg * 16));
        }
        #pragma unroll
        for (int ct = 0; ct < 4; ++ct) {
            const int col = wc * 64 + ct * 16 + l15;
            bF[ct] = *(const bf8*)((const char*)B_lds + col * 256 + SWZ(col, ks * 64 + lg * 16));
        }
        #pragma unroll
        for (int rt = 0; rt < 2; ++rt)
            #pragma unroll
            for (int ct = 0; ct < 4; ++ct)
                acc[rt][ct] = __builtin_amdgcn_mfma_f32_16x16x32_bf16(aF[rt], bF[ct], acc[rt][ct], 0, 0, 0);
    }

    #pragma unroll
    for (int rt = 0; rt < 2; ++rt) {
        const int ltree = wr * 2 + rt;
        #pragma unroll
        for (int ct = 0; ct < 4; ++ct) {
            const int col = wc * 64 + ct * 16 + l15;
            const float bcv = bc[col];
            f32x4 v = acc[rt][ct];
            float m = -1e30f;
            #pragma unroll
            for (int r = 0; r < 4; ++r)
                m = fmaxf(m, v[r] + c_cnt[lg * 4 + r] * bcv);
            m = fmaxf(m, __shfl_xor(m, 16));
            m = fmaxf(m, __shfl_xor(m, 32));
            m = fmaxf(m, 0.f);
            if (lg == 0) {
                const int gtree = tree0 + ltree;
                const int row = (gtree & 127) * 64 + (gtree >> 7);   // t*64 + b
                enc_bf[((size_t)e * NTREE + row) * EE + col] = f2bf(m);
            }
        }
    }
}

// ---------------------------------------------------------------------------
// K2: G = enc @ wih_pad^T + bias -> bf16 G[16384][768]. Each n-block is one
// (dir, gate) slab of 128 padded j; pad cols come out exactly 0.
// ---------------------------------------------------------------------------
__global__ __launch_bounds__(512) void k_gi(
    const unsigned short* __restrict__ enc_bf,
    const unsigned short* __restrict__ wih_pad,
    const float* __restrict__ bih_f, const float* __restrict__ bih_b,
    unsigned short* __restrict__ G_bf)
{
    __shared__ unsigned short A_lds[128 * 128];
    __shared__ unsigned short B_lds[128 * 128];
    const int tid = threadIdx.x;
    const int m0 = blockIdx.x * 128;
    const int n0 = blockIdx.y * 128;
    const int dir = blockIdx.y / 3, g = blockIdx.y % 3;
    const float* __restrict__ bih = dir ? bih_b : bih_f;

    #pragma unroll
    for (int it = 0; it < 4; ++it) {
        const int idx = tid + 512 * it;
        const int row = idx >> 4, seg = idx & 15;
        u32x4 v = *(const u32x4*)(enc_bf + (size_t)(m0 + row) * EE + seg * 8);
        *(u32x4*)((char*)A_lds + row * 256 + SWZ(row, seg * 16)) = v;
        u32x4 w = *(const u32x4*)(wih_pad + (size_t)(n0 + row) * EE + seg * 8);
        *(u32x4*)((char*)B_lds + row * 256 + SWZ(row, seg * 16)) = w;
    }
    __syncthreads();

    const int wid = tid >> 6, lane = tid & 63;
    const int wr = wid >> 1, wc = wid & 1;
    const int l15 = lane & 15, lg = lane >> 4;

    f32x4 acc[2][4];
    #pragma unroll
    for (int rt = 0; rt < 2; ++rt)
        #pragma unroll
        for (int ct = 0; ct < 4; ++ct) acc[rt][ct] = (f32x4){0.f, 0.f, 0.f, 0.f};

    #pragma unroll
    for (int ks = 0; ks < 4; ++ks) {
        bf8 aF[2], bF[4];
        #pragma unroll
        for (int rt = 0; rt < 2; ++rt) {
            const int row = wr * 32 + rt * 16 + l15;
            aF[rt] = *(const bf8*)((const char*)A_lds + row * 256 + SWZ(row, ks * 64 + lg * 16));
        }
        #pragma unroll
        for (int ct = 0; ct < 4; ++ct) {
            const int col = wc * 64 + ct * 16 + l15;
            bF[ct] = *(const bf8*)((const char*)B_lds + col * 256 + SWZ(col, ks * 64 + lg * 16));
        }
        #pragma unroll
        for (int rt = 0; rt < 2; ++rt)
            #pragma unroll
            for (int ct = 0; ct < 4; ++ct)
                acc[rt][ct] = __builtin_amdgcn_mfma_f32_16x16x32_bf16(aF[rt], bF[ct], acc[rt][ct], 0, 0, 0);
    }

    #pragma unroll
    for (int rt = 0; rt < 2; ++rt) {
        #pragma unroll
        for (int ct = 0; ct < 4; ++ct) {
            const int col = wc * 64 + ct * 16 + l15;     // j within slab
            const float bias = (col < 100) ? bih[g * 100 + col] : 0.f;
            #pragma unroll
            for (int r = 0; r < 4; ++r) {
                const int row = wr * 32 + rt * 16 + lg * 4 + r;
                G_bf[(size_t)(m0 + row) * 768 + n0 + col] = f2bf(acc[rt][ct][r] + bias);
            }
        }
    }
}

// ---------------------------------------------------------------------------
// K3: GRU scan via MFMA. 16 blocks (e,dir,bgroup16) x 512 thr (8 waves).
// gh^T = whh_pad . h^T : A = whh (const, regs), B = h (bf16 LDS, dbuf).
// Lane slots: b = b0 + (lane&15), j = wave*16 + (lane>>4)*4 + r.
// gi prefetched 1 step ahead (3 x 8B per lane). 1 barrier per step.
// ---------------------------------------------------------------------------
__global__ __launch_bounds__(512) void k_gru(
    const unsigned short* __restrict__ G_bf,
    const unsigned short* __restrict__ whh_pad,
    const float* __restrict__ bhh_f, const float* __restrict__ bhh_b,
    float* __restrict__ hmax_out)
{
    __shared__ unsigned short h_lds[2][16 * 128];   // [buf][b][k] swizzled, 8KB
    const int tid  = threadIdx.x;
    const int blk  = blockIdx.x;        // 16
    const int e    = blk >> 3;
    const int dir  = (blk >> 2) & 1;
    const int b0   = (blk & 3) * 16;
    const int w    = tid >> 6;
    const int lane = tid & 63;
    const int l15  = lane & 15;
    const int lg   = lane >> 4;
    const int jbase = w * 16;
    const bool active = (w < 7);        // wave 7 covers only pad rows j>=112

    // zero both h buffers (16KB total, 512 thr x 16B... 2*2048 ushorts /8 = 512)
    ((u32x4*)h_lds)[tid] = (u32x4){0u, 0u, 0u, 0u};

    bf8 aF[3][4];
    float bh[3][4];
    if (active) {
        const unsigned short* wp = whh_pad + (size_t)dir * 3 * 128 * 128;
        #pragma unroll
        for (int g = 0; g < 3; ++g)
            #pragma unroll
            for (int ks = 0; ks < 4; ++ks)
                aF[g][ks] = *(const bf8*)(wp + (size_t)(g * 128 + jbase + l15) * 128 + ks * 32 + lg * 8);
        const float* bhh = dir ? bhh_b : bhh_f;
        #pragma unroll
        for (int g = 0; g < 3; ++g)
            #pragma unroll
            for (int r = 0; r < 4; ++r) {
                const int j = jbase + lg * 4 + r;
                bh[g][r] = (j < 100) ? bhh[g * 100 + j] : 0.f;
            }
    }

    const unsigned short* gptr = G_bf
        + ((size_t)(e * 8192 + b0 + l15)) * 768 + dir * 384 + jbase + lg * 4;

    ushort4 gp_n[3] = {};
    if (active) {
        const int tm0 = dir ? 127 : 0;
        #pragma unroll
        for (int g = 0; g < 3; ++g)
            gp_n[g] = *(const ushort4*)(gptr + (size_t)tm0 * 49152 + g * 128);
    }

    float h_reg[4] = {0.f, 0.f, 0.f, 0.f};
    float hmx[4]   = {-1e30f, -1e30f, -1e30f, -1e30f};
    __syncthreads();

    for (int t = 0; t < S_; ++t) {
        const int p = t & 1;
        bf8 bF[4];
        if (active) {
            const char* hb = (const char*)h_lds + p * 4096;
            #pragma unroll
            for (int ks = 0; ks < 4; ++ks) {
                const int o = ks * 64 + lg * 16;
                bF[ks] = *(const bf8*)(hb + l15 * 256 + (o ^ ((l15 & 7) << 4)));
            }
        }
        ushort4 gp[3];
        #pragma unroll
        for (int g = 0; g < 3; ++g) gp[g] = gp_n[g];
        if (active && t + 1 < S_) {
            const int tm = dir ? (126 - t) : (t + 1);
            #pragma unroll
            for (int g = 0; g < 3; ++g)
                gp_n[g] = *(const ushort4*)(gptr + (size_t)tm * 49152 + g * 128);
        }
        if (active) {
            f32x4 acc[3];
            #pragma unroll
            for (int g = 0; g < 3; ++g) acc[g] = (f32x4){0.f, 0.f, 0.f, 0.f};
            #pragma unroll
            for (int ks = 0; ks < 4; ++ks)
                #pragma unroll
                for (int g = 0; g < 3; ++g)
                    acc[g] = __builtin_amdgcn_mfma_f32_16x16x32_bf16(aF[g][ks], bF[ks], acc[g], 0, 0, 0);

            ushort4 hq;
            unsigned short hqv[4];
            #pragma unroll
            for (int r = 0; r < 4; ++r) {
                const float ir  = bfq(gp[0], r);
                const float iz  = bfq(gp[1], r);
                const float in_ = bfq(gp[2], r);
                const float hr = acc[0][r] + bh[0][r];
                const float hz = acc[1][r] + bh[1][r];
                const float hn = acc[2][r] + bh[2][r];
                const float rg = 1.f / (1.f + __expf(-(ir + hr)));
                const float zg = 1.f / (1.f + __expf(-(iz + hz)));
                float nx = in_ + rg * hn;
                nx = fminf(fmaxf(nx, -15.f), 15.f);
                const float ex = __expf(2.f * nx);
                const float ng = 1.f - 2.f / (ex + 1.f);
                float hnew = ng + zg * (h_reg[r] - ng);
                const int j = jbase + lg * 4 + r;
                if (j >= 100) hnew = 0.f;
                h_reg[r] = hnew;
                hmx[r] = fmaxf(hmx[r], hnew);
                hqv[r] = f2bf(hnew);
            }
            hq.x = hqv[0]; hq.y = hqv[1]; hq.z = hqv[2]; hq.w = hqv[3];
            const int o = (jbase + lg * 4) * 2;
            const int so = ((o & ~15) ^ ((l15 & 7) << 4)) | (o & 15);
            *(ushort4*)((char*)h_lds + (p ^ 1) * 4096 + l15 * 256 + so) = hq;
        }
        __syncthreads();
    }

    if (active) {
        #pragma unroll
        for (int r = 0; r < 4; ++r) {
            const int j = jbase + lg * 4 + r;
            if (j < 100)
                hmax_out[((size_t)((e * 2 + dir) * 64 + b0 + l15)) * HH + j] = hmx[r];
        }
    }
}

// ---------------------------------------------------------------------------
// K4: fc + softmax
// ---------------------------------------------------------------------------
__global__ void k_final(const float* __restrict__ hmax,
                        const float* __restrict__ fcw,
                        const float* __restrict__ fcb,
                        float* __restrict__ out)
{
    const int b = threadIdx.x;
    if (b >= B_) return;
    float y0 = fcb[0], y1 = fcb[1];
    for (int m = 0; m < 400; ++m) {
        const int e   = m / 200;
        const int dm  = m % 200;
        const int dir = dm / 100;
        const int j   = dm % 100;
        const float x = hmax[((size_t)((e * 2 + dir) * 64 + b)) * HH + j];
        y0 += fcw[m]       * x;
        y1 += fcw[400 + m] * x;
    }
    const float mx = fmaxf(y0, y1);
    const float e0 = __expf(y0 - mx), e1 = __expf(y1 - mx);
    const float s = e0 + e1;
    out[b * 2]     = e0 / s;
    out[b * 2 + 1] = e1 / s;
}

extern "C" void kernel_launch(void* const* d_in, const int* in_sizes, int n_in,
                              void* d_out, int out_size, void* d_ws, size_t ws_size,
                              hipStream_t stream)
{
    const int*   tok1  = (const int*)d_in[0];
    const int*   tok2  = (const int*)d_in[1];
    const float* emb   = (const float*)d_in[4];
    const float* Wc    = (const float*)d_in[5];
    const float* bc    = (const float*)d_in[6];
    const float* wih_f = (const float*)d_in[7];
    const float* whh_f = (const float*)d_in[8];
    const float* bih_f = (const float*)d_in[9];
    const float* bhh_f = (const float*)d_in[10];
    const float* wih_b = (const float*)d_in[11];
    const float* whh_b = (const float*)d_in[12];
    const float* bih_b = (const float*)d_in[13];
    const float* bhh_b = (const float*)d_in[14];
    const float* fcw   = (const float*)d_in[15];
    const float* fcb   = (const float*)d_in[16];

    char* ws = (char*)d_ws;
    unsigned short* emb_bf  = (unsigned short*)(ws + EMB_BF_OFF);
    unsigned short* wc_bf   = (unsigned short*)(ws + WC_BF_OFF);
    unsigned short* wih_pad = (unsigned short*)(ws + WIH_BF_OFF);
    unsigned short* whh_pad = (unsigned short*)(ws + WHH_BF_OFF);
    unsigned short* enc_bf  = (unsigned short*)(ws + ENC_BF_OFF);
    unsigned short* G_bf    = (unsigned short*)(ws + G_BF_OFF);
    float*          hmax    = (float*)(ws + HMAX_OFF);

    k_prep<<<6458, 256, 0, stream>>>(emb, Wc, wih_f, wih_b, whh_f, whh_b,
                                     emb_bf, wc_bf, wih_pad, whh_pad);
    k_encode<<<2048, 512, 0, stream>>>(tok1, tok2, emb_bf, wc_bf, bc, enc_bf);
    k_gi<<<dim3(128, 6), 512, 0, stream>>>(enc_bf, wih_pad, bih_f, bih_b, G_bf);
    k_gru<<<16, 512, 0, stream>>>(G_bf, whh_pad, bhh_f, bhh_b, hmax);
    k_final<<<1, 64, 0, stream>>>(hmax, fcw, fcb, (float*)d_out);
}

// Round 4
// 200.797 us; speedup vs baseline: 1.6985x; 1.6985x over previous
//
#include <hip/hip_runtime.h>
#include <math.h>

#define B_      64
#define S_      128
#define KN      16
#define EE      128
#define HH      100
#define NTREE   8192            // B_*S_

typedef __attribute__((ext_vector_type(8))) short   bf8;    // 8 bf16 (4 VGPRs)
typedef __attribute__((ext_vector_type(4))) float   f32x4;
typedef __attribute__((ext_vector_type(8))) float   f32x8;
typedef __attribute__((ext_vector_type(4))) unsigned int u32x4;

// workspace byte offsets (256-aligned)
#define EMB_BF_OFF   0u           // 50000*128*2 = 12,800,000
#define WC_BF_OFF    12800000u    // 128*128*2   = 32,768
#define WIH_BF_OFF   12832768u    // 768*128*2   = 196,608 (padded [dir][g][128j][128k])
#define WHH_BF_OFF   13029376u    // 768*128*2   = 196,608 (padded, zero pads)
#define ENC_BF_OFF   13225984u    // 16384*128*2 = 4,194,304   rows = e*8192 + t*64 + b
#define HMAX_OFF     17420288u    // 25600*4     = 102,400

__constant__ float c_cnt[16] = {16.f,8.f,7.f,4.f,3.f,3.f,3.f,2.f,
                                1.f,1.f,1.f,1.f,1.f,1.f,1.f,1.f};

__device__ __forceinline__ float bf2f(unsigned short u) {
    unsigned int x = ((unsigned int)u) << 16;
    return __builtin_bit_cast(float, x);
}
__device__ __forceinline__ unsigned short f2bf(float f) {
    unsigned int x = __builtin_bit_cast(unsigned int, f);
    x = x + 0x7fffu + ((x >> 16) & 1u);          // RNE
    return (unsigned short)(x >> 16);
}
// swizzle a 16B-aligned column-byte offset within a 256B row
#define SWZ(row, cb) ((cb) ^ (((row) & 7) << 4))

// ---------------------------------------------------------------------------
// K0: fp32 -> bf16 prep: emb, Wc, wih padded [2][3][128][128], whh padded same
// ---------------------------------------------------------------------------
#define NA 1600000   // emb float4s
#define NB 4096      // Wc float4s
#define NC 24576     // wih_pad ushort4s (768*128/4)
#define ND 24576     // whh_pad ushort4s
__global__ __launch_bounds__(256) void k_prep(
    const float* __restrict__ emb, const float* __restrict__ Wc,
    const float* __restrict__ wih_f, const float* __restrict__ wih_b,
    const float* __restrict__ whh_f, const float* __restrict__ whh_b,
    unsigned short* __restrict__ emb_bf, unsigned short* __restrict__ wc_bf,
    unsigned short* __restrict__ wih_pad, unsigned short* __restrict__ whh_pad)
{
    const int i = blockIdx.x * 256 + threadIdx.x;
    if (i < NA + NB) {
        const float* src = (i < NA) ? emb : Wc;
        unsigned short* dst = (i < NA) ? emb_bf : wc_bf;
        const int j = (i < NA) ? i : i - NA;
        float4 v = ((const float4*)src)[j];
        ushort4 o;
        o.x = f2bf(v.x); o.y = f2bf(v.y); o.z = f2bf(v.z); o.w = f2bf(v.w);
        ((ushort4*)dst)[j] = o;
    } else if (i < NA + NB + NC) {
        const int u = i - NA - NB;                  // 0..24575
        const int row = u >> 5, k4 = u & 31;        // row 0..767
        const int dir = row / 384, rem = row % 384, g = rem >> 7, j = rem & 127;
        ushort4 o = {0, 0, 0, 0};
        if (j < 100) {
            const float* w = dir ? wih_b : wih_f;   // [300][128]
            float4 v = ((const float4*)w)[(g * 100 + j) * 32 + k4];
            o.x = f2bf(v.x); o.y = f2bf(v.y); o.z = f2bf(v.z); o.w = f2bf(v.w);
        }
        ((ushort4*)wih_pad)[u] = o;
    } else if (i < NA + NB + NC + ND) {
        const int u = i - NA - NB - NC;
        const int row = u >> 5, k0 = (u & 31) * 4;
        const int dir = row / 384, rem = row % 384, g = rem >> 7, j = rem & 127;
        ushort4 o = {0, 0, 0, 0};
        if (j < 100) {
            const float* w = dir ? whh_b : whh_f;   // [300][100]
            const float* wr = w + (g * 100 + j) * 100;
            unsigned short t[4];
            #pragma unroll
            for (int q = 0; q < 4; ++q)
                t[q] = (k0 + q < 100) ? f2bf(wr[k0 + q]) : (unsigned short)0;
            o.x = t[0]; o.y = t[1]; o.z = t[2]; o.w = t[3];
        }
        ((ushort4*)whh_pad)[u] = o;
    }
}

// ---------------------------------------------------------------------------
// K1: gather bf16 emb -> register tree-aggregate -> bf16 A tile; B = Wc bf16.
// MFMA 16x16x32; epilogue: +cnt*bc, per-tree max over 16 nodes, relu.
// enc rows stored as e*8192 + t*64 + b (GRU-friendly order).
// ---------------------------------------------------------------------------
__global__ __launch_bounds__(512) void k_encode(
    const int* __restrict__ tok1, const int* __restrict__ tok2,
    const unsigned short* __restrict__ emb_bf,
    const unsigned short* __restrict__ wc_bf,
    const float* __restrict__ bc,
    unsigned short* __restrict__ enc_bf)
{
    __shared__ unsigned short A_lds[128 * 128];   // [row][k] swizzled
    __shared__ unsigned short B_lds[128 * 128];   // [col][k] swizzled
    const int tid = threadIdx.x;
    const int blk = blockIdx.x;
    const int e = blk >> 10;
    const int tree0 = (blk & 1023) * 8;
    const int* __restrict__ tok = e ? tok2 : tok1;

    if (tid < 128) {
        const int tr = tid >> 4, seg = tid & 15;
        const int tb = (tree0 + tr) * KN;
        int tkn[16];
        #pragma unroll
        for (int n = 0; n < 16; ++n) tkn[n] = tok[tb + n];
        f32x8 a[16];
        #pragma unroll
        for (int n = 0; n < 16; ++n) {
            bf8 v = *(const bf8*)(emb_bf + (size_t)tkn[n] * EE + seg * 8);
            f32x8 f;
            #pragma unroll
            for (int q = 0; q < 8; ++q) f[q] = bf2f((unsigned short)v[q]);
            a[n] = f;
        }
        a[7] += a[15];
        a[3] += a[7]  + a[8];   a[4] += a[9]  + a[10];
        a[5] += a[11] + a[12];  a[6] += a[13] + a[14];
        a[1] += a[3]  + a[4];   a[2] += a[5]  + a[6];
        a[0] += a[1]  + a[2];
        #pragma unroll
        for (int n = 0; n < 16; ++n) {
            const int row = tr * 16 + n;
            bf8 o;
            #pragma unroll
            for (int q = 0; q < 8; ++q) o[q] = (short)f2bf(a[n][q]);
            *(bf8*)((char*)A_lds + row * 256 + SWZ(row, seg * 16)) = o;
        }
    } else if (tid >= 256) {
        const int u0 = tid - 256;
        #pragma unroll
        for (int it = 0; it < 8; ++it) {
            const int idx = u0 + 256 * it;
            const int row = idx >> 4, seg = idx & 15;
            u32x4 v = *(const u32x4*)(wc_bf + row * EE + seg * 8);
            *(u32x4*)((char*)B_lds + row * 256 + SWZ(row, seg * 16)) = v;
        }
    }
    __syncthreads();

    const int wid = tid >> 6, lane = tid & 63;
    const int wr = wid >> 1, wc = wid & 1;
    const int l15 = lane & 15, lg = lane >> 4;

    f32x4 acc[2][4];
    #pragma unroll
    for (int rt = 0; rt < 2; ++rt)
        #pragma unroll
        for (int ct = 0; ct < 4; ++ct) acc[rt][ct] = (f32x4){0.f, 0.f, 0.f, 0.f};

    #pragma unroll
    for (int ks = 0; ks < 4; ++ks) {
        bf8 aF[2], bF[4];
        #pragma unroll
        for (int rt = 0; rt < 2; ++rt) {
            const int row = wr * 32 + rt * 16 + l15;
            aF[rt] = *(const bf8*)((const char*)A_lds + row * 256 + SWZ(row, ks * 64 + lg * 16));
        }
        #pragma unroll
        for (int ct = 0; ct < 4; ++ct) {
            const int col = wc * 64 + ct * 16 + l15;
            bF[ct] = *(const bf8*)((const char*)B_lds + col * 256 + SWZ(col, ks * 64 + lg * 16));
        }
        #pragma unroll
        for (int rt = 0; rt < 2; ++rt)
            #pragma unroll
            for (int ct = 0; ct < 4; ++ct)
                acc[rt][ct] = __builtin_amdgcn_mfma_f32_16x16x32_bf16(aF[rt], bF[ct], acc[rt][ct], 0, 0, 0);
    }

    #pragma unroll
    for (int rt = 0; rt < 2; ++rt) {
        const int ltree = wr * 2 + rt;
        #pragma unroll
        for (int ct = 0; ct < 4; ++ct) {
            const int col = wc * 64 + ct * 16 + l15;
            const float bcv = bc[col];
            f32x4 v = acc[rt][ct];
            float m = -1e30f;
            #pragma unroll
            for (int r = 0; r < 4; ++r)
                m = fmaxf(m, v[r] + c_cnt[lg * 4 + r] * bcv);
            m = fmaxf(m, __shfl_xor(m, 16));
            m = fmaxf(m, __shfl_xor(m, 32));
            m = fmaxf(m, 0.f);
            if (lg == 0) {
                const int gtree = tree0 + ltree;
                const int row = (gtree & 127) * 64 + (gtree >> 7);   // t*64 + b
                enc_bf[((size_t)e * NTREE + row) * EE + col] = f2bf(m);
            }
        }
    }
}

// ---------------------------------------------------------------------------
// K3: fused GRU scan. 16 blocks (e,dir,bgroup16) x 448 thr (7 waves).
// Per step per wave: gi = wih.enc[t] (12 MFMA, B-frags direct from global,
// depth-2 prefetch) + gh = whh.h (12 MFMA, h from LDS dbuf). Weight frags
// (wih+whh, 24 bf8) live in registers. Gates in fp32 with v_rcp (no divide).
// One barrier per step. Lane slots: b=b0+(lane&15), j=w*16+(lane>>4)*4+r.
// ---------------------------------------------------------------------------
__global__ __launch_bounds__(448, 2) void k_gru(
    const unsigned short* __restrict__ enc_bf,
    const unsigned short* __restrict__ wih_pad,
    const unsigned short* __restrict__ whh_pad,
    const float* __restrict__ bih_f, const float* __restrict__ bih_b,
    const float* __restrict__ bhh_f, const float* __restrict__ bhh_b,
    float* __restrict__ hmax_out)
{
    __shared__ unsigned short h_lds[2][16 * 128];   // [buf][b][k] swizzled, 8KB
    const int tid  = threadIdx.x;
    const int blk  = blockIdx.x;        // 16
    const int e    = blk >> 3;
    const int dir  = (blk >> 2) & 1;
    const int b0   = (blk & 3) * 16;
    const int w    = tid >> 6;
    const int lane = tid & 63;
    const int l15  = lane & 15;
    const int lg   = lane >> 4;
    const int jbase = w * 16;

    // zero both h buffers (8KB = 512 x 16B)
    for (int u = tid; u < 512; u += 448)
        ((u32x4*)h_lds)[u] = (u32x4){0u, 0u, 0u, 0u};

    // weight fragments: A[j=jbase+l15][k=ks*32+lg*8 ..+8]
    bf8 aI[3][4], aH[3][4];
    {
        const unsigned short* wiP = wih_pad + (size_t)dir * 3 * 128 * 128;
        const unsigned short* whP = whh_pad + (size_t)dir * 3 * 128 * 128;
        #pragma unroll
        for (int g = 0; g < 3; ++g)
            #pragma unroll
            for (int ks = 0; ks < 4; ++ks) {
                const size_t ro = (size_t)(g * 128 + jbase + l15) * 128 + ks * 32 + lg * 8;
                aI[g][ks] = *(const bf8*)(wiP + ro);
                aH[g][ks] = *(const bf8*)(whP + ro);
            }
    }
    const float* __restrict__ bih = dir ? bih_b : bih_f;
    const float* __restrict__ bhh = dir ? bhh_b : bhh_f;
    float bsr[4], bsz[4], bin[4], bhn[4];
    #pragma unroll
    for (int r = 0; r < 4; ++r) {
        const int j = jbase + lg * 4 + r;
        bsr[r] = (j < 100) ? bih[j]       + bhh[j]       : 0.f;
        bsz[r] = (j < 100) ? bih[100 + j] + bhh[100 + j] : 0.f;
        bin[r] = (j < 100) ? bih[200 + j] : 0.f;
        bhn[r] = (j < 100) ? bhh[200 + j] : 0.f;
    }

    const unsigned short* encp =
        enc_bf + ((size_t)e * NTREE + b0 + l15) * EE + lg * 8;

    // depth-2 prefetch of enc B-fragments
    bf8 eA[4], eB[4];
    {
        const int tm0 = dir ? 127 : 0;
        const int tm1 = dir ? 126 : 1;
        #pragma unroll
        for (int ks = 0; ks < 4; ++ks) {
            eA[ks] = *(const bf8*)(encp + (size_t)tm0 * 8192 + ks * 32);
            eB[ks] = *(const bf8*)(encp + (size_t)tm1 * 8192 + ks * 32);
        }
    }

    float h_reg[4] = {0.f, 0.f, 0.f, 0.f};
    float hmx[4]   = {-1e30f, -1e30f, -1e30f, -1e30f};
    __syncthreads();

#define GRU_STEP(EF, P, PT)                                                    \
    {                                                                          \
        bf8 hF[4];                                                             \
        const char* hb = (const char*)h_lds + (P) * 4096 + l15 * 256;          \
        _Pragma("unroll")                                                      \
        for (int ks = 0; ks < 4; ++ks)                                         \
            hF[ks] = *(const bf8*)(hb + ((ks * 64 + lg * 16) ^ ((l15 & 7) << 4))); \
        f32x4 accI[3], accH[3];                                                \
        _Pragma("unroll")                                                      \
        for (int g = 0; g < 3; ++g) {                                          \
            accI[g] = (f32x4){0.f, 0.f, 0.f, 0.f};                             \
            accH[g] = (f32x4){0.f, 0.f, 0.f, 0.f};                             \
        }                                                                      \
        _Pragma("unroll")                                                      \
        for (int ks = 0; ks < 4; ++ks) {                                       \
            _Pragma("unroll")                                                  \
            for (int g = 0; g < 3; ++g) {                                      \
                accI[g] = __builtin_amdgcn_mfma_f32_16x16x32_bf16(aI[g][ks], EF[ks], accI[g], 0, 0, 0); \
                accH[g] = __builtin_amdgcn_mfma_f32_16x16x32_bf16(aH[g][ks], hF[ks], accH[g], 0, 0, 0); \
            }                                                                  \
        }                                                                      \
        if ((PT) < S_) {                                                       \
            const int tmn = dir ? (127 - (PT)) : (PT);                         \
            _Pragma("unroll")                                                  \
            for (int ks = 0; ks < 4; ++ks)                                     \
                EF[ks] = *(const bf8*)(encp + (size_t)tmn * 8192 + ks * 32);   \
        }                                                                      \
        unsigned short hq[4];                                                  \
        _Pragma("unroll")                                                      \
        for (int r = 0; r < 4; ++r) {                                          \
            const float xr  = accI[0][r] + accH[0][r] + bsr[r];                \
            const float xz  = accI[1][r] + accH[1][r] + bsz[r];                \
            const float in_ = accI[2][r] + bin[r];                             \
            const float hn  = accH[2][r] + bhn[r];                             \
            const float rg  = __builtin_amdgcn_rcpf(1.f + __expf(-xr));        \
            const float zg  = __builtin_amdgcn_rcpf(1.f + __expf(-xz));        \
            float nx = in_ + rg * hn;                                          \
            nx = fminf(fmaxf(nx, -15.f), 15.f);                                \
            const float ng = 1.f - 2.f * __builtin_amdgcn_rcpf(__expf(2.f * nx) + 1.f); \
            float hnew = ng + zg * (h_reg[r] - ng);                            \
            if (jbase + lg * 4 + r >= 100) hnew = 0.f;                         \
            h_reg[r] = hnew;                                                   \
            hmx[r] = fmaxf(hmx[r], hnew);                                      \
            hq[r] = f2bf(hnew);                                                \
        }                                                                      \
        {                                                                      \
            const int o  = (jbase + lg * 4) * 2;                               \
            const int so = ((o & ~15) ^ ((l15 & 7) << 4)) | (o & 15);          \
            ushort4 hv; hv.x = hq[0]; hv.y = hq[1]; hv.z = hq[2]; hv.w = hq[3];\
            *(ushort4*)((char*)h_lds + ((P) ^ 1) * 4096 + l15 * 256 + so) = hv;\
        }                                                                      \
        __syncthreads();                                                       \
    }

    for (int t = 0; t < S_; t += 2) {
        GRU_STEP(eA, 0, t + 2)
        GRU_STEP(eB, 1, t + 3)
    }
#undef GRU_STEP

    #pragma unroll
    for (int r = 0; r < 4; ++r) {
        const int j = jbase + lg * 4 + r;
        if (j < 100)
            hmax_out[((size_t)((e * 2 + dir) * 64 + b0 + l15)) * HH + j] = hmx[r];
    }
}

// ---------------------------------------------------------------------------
// K4: fc + softmax
// ---------------------------------------------------------------------------
__global__ void k_final(const float* __restrict__ hmax,
                        const float* __restrict__ fcw,
                        const float* __restrict__ fcb,
                        float* __restrict__ out)
{
    const int b = threadIdx.x;
    if (b >= B_) return;
    float y0 = fcb[0], y1 = fcb[1];
    for (int m = 0; m < 400; ++m) {
        const int e   = m / 200;
        const int dm  = m % 200;
        const int dir = dm / 100;
        const int j   = dm % 100;
        const float x = hmax[((size_t)((e * 2 + dir) * 64 + b)) * HH + j];
        y0 += fcw[m]       * x;
        y1 += fcw[400 + m] * x;
    }
    const float mx = fmaxf(y0, y1);
    const float e0 = __expf(y0 - mx), e1 = __expf(y1 - mx);
    const float s = e0 + e1;
    out[b * 2]     = e0 / s;
    out[b * 2 + 1] = e1 / s;
}

extern "C" void kernel_launch(void* const* d_in, const int* in_sizes, int n_in,
                              void* d_out, int out_size, void* d_ws, size_t ws_size,
                              hipStream_t stream)
{
    const int*   tok1  = (const int*)d_in[0];
    const int*   tok2  = (const int*)d_in[1];
    const float* emb   = (const float*)d_in[4];
    const float* Wc    = (const float*)d_in[5];
    const float* bc    = (const float*)d_in[6];
    const float* wih_f = (const float*)d_in[7];
    const float* whh_f = (const float*)d_in[8];
    const float* bih_f = (const float*)d_in[9];
    const float* bhh_f = (const float*)d_in[10];
    const float* wih_b = (const float*)d_in[11];
    const float* whh_b = (const float*)d_in[12];
    const float* bih_b = (const float*)d_in[13];
    const float* bhh_b = (const float*)d_in[14];
    const float* fcw   = (const float*)d_in[15];
    const float* fcb   = (const float*)d_in[16];

    char* ws = (char*)d_ws;
    unsigned short* emb_bf  = (unsigned short*)(ws + EMB_BF_OFF);
    unsigned short* wc_bf   = (unsigned short*)(ws + WC_BF_OFF);
    unsigned short* wih_pad = (unsigned short*)(ws + WIH_BF_OFF);
    unsigned short* whh_pad = (unsigned short*)(ws + WHH_BF_OFF);
    unsigned short* enc_bf  = (unsigned short*)(ws + ENC_BF_OFF);
    float*          hmax    = (float*)(ws + HMAX_OFF);

    k_prep<<<6458, 256, 0, stream>>>(emb, Wc, wih_f, wih_b, whh_f, whh_b,
                                     emb_bf, wc_bf, wih_pad, whh_pad);
    k_encode<<<2048, 512, 0, stream>>>(tok1, tok2, emb_bf, wc_bf, bc, enc_bf);
    k_gru<<<16, 448, 0, stream>>>(enc_bf, wih_pad, whh_pad,
                                  bih_f, bih_b, bhh_f, bhh_b, hmax);
    k_final<<<1, 64, 0, stream>>>(hmax, fcw, fcb, (float*)d_out);
}

// Round 5
// 192.075 us; speedup vs baseline: 1.7757x; 1.0454x over previous
//
#include <hip/hip_runtime.h>
#include <math.h>

#define B_      64
#define S_      128
#define KN      16
#define EE      128
#define HH      100
#define NTREE   8192            // B_*S_

typedef __attribute__((ext_vector_type(8))) short   bf8;    // 8 bf16 (4 VGPRs)
typedef __attribute__((ext_vector_type(4))) float   f32x4;
typedef __attribute__((ext_vector_type(8))) float   f32x8;
typedef __attribute__((ext_vector_type(4))) unsigned int u32x4;

// workspace byte offsets (256-aligned)
#define EMB_BF_OFF   0u           // 50000*128*2 = 12,800,000
#define WC_BF_OFF    12800000u    // 128*128*2   = 32,768
#define WIH_BF_OFF   12832768u    // 768*128*2   = 196,608 (padded [dir][g][128j][128k])
#define WHH_BF_OFF   13029376u    // 768*128*2   = 196,608 (padded, zero pads)
#define ENC_BF_OFF   13225984u    // 16384*128*2 = 4,194,304   rows = e*8192 + t*64 + b
#define HMAX_OFF     17420288u    // 25600*4     = 102,400

__constant__ float c_cnt[16] = {16.f,8.f,7.f,4.f,3.f,3.f,3.f,2.f,
                                1.f,1.f,1.f,1.f,1.f,1.f,1.f,1.f};

__device__ __forceinline__ float bf2f(unsigned short u) {
    unsigned int x = ((unsigned int)u) << 16;
    return __builtin_bit_cast(float, x);
}
__device__ __forceinline__ unsigned short f2bf(float f) {
    unsigned int x = __builtin_bit_cast(unsigned int, f);
    x = x + 0x7fffu + ((x >> 16) & 1u);          // RNE
    return (unsigned short)(x >> 16);
}
__device__ __forceinline__ f32x8 cvt8(const bf8& v) {
    f32x8 f;
    #pragma unroll
    for (int q = 0; q < 8; ++q) f[q] = bf2f((unsigned short)v[q]);
    return f;
}
__device__ __forceinline__ f32x8 shx(const f32x8& v, int m) {
    f32x8 o;
    #pragma unroll
    for (int q = 0; q < 8; ++q) o[q] = __shfl_xor(v[q], m);
    return o;
}
__device__ __forceinline__ bf8 pack8(const f32x8& v) {
    bf8 o;
    #pragma unroll
    for (int q = 0; q < 8; ++q) o[q] = (short)f2bf(v[q]);
    return o;
}
// swizzle a 16B-aligned column-byte offset within a 256B row
#define SWZ(row, cb) ((cb) ^ (((row) & 7) << 4))

// ---------------------------------------------------------------------------
// K0: fp32 -> bf16 prep: emb, Wc, wih padded [2][3][128][128], whh padded same
// ---------------------------------------------------------------------------
#define NA 1600000   // emb float4s
#define NB 4096      // Wc float4s
#define NC 24576     // wih_pad ushort4s (768*128/4)
#define ND 24576     // whh_pad ushort4s
__global__ __launch_bounds__(256) void k_prep(
    const float* __restrict__ emb, const float* __restrict__ Wc,
    const float* __restrict__ wih_f, const float* __restrict__ wih_b,
    const float* __restrict__ whh_f, const float* __restrict__ whh_b,
    unsigned short* __restrict__ emb_bf, unsigned short* __restrict__ wc_bf,
    unsigned short* __restrict__ wih_pad, unsigned short* __restrict__ whh_pad)
{
    const int i = blockIdx.x * 256 + threadIdx.x;
    if (i < NA + NB) {
        const float* src = (i < NA) ? emb : Wc;
        unsigned short* dst = (i < NA) ? emb_bf : wc_bf;
        const int j = (i < NA) ? i : i - NA;
        float4 v = ((const float4*)src)[j];
        ushort4 o;
        o.x = f2bf(v.x); o.y = f2bf(v.y); o.z = f2bf(v.z); o.w = f2bf(v.w);
        ((ushort4*)dst)[j] = o;
    } else if (i < NA + NB + NC) {
        const int u = i - NA - NB;                  // 0..24575
        const int row = u >> 5, k4 = u & 31;        // row 0..767
        const int dir = row / 384, rem = row % 384, g = rem >> 7, j = rem & 127;
        ushort4 o = {0, 0, 0, 0};
        if (j < 100) {
            const float* w = dir ? wih_b : wih_f;   // [300][128]
            float4 v = ((const float4*)w)[(g * 100 + j) * 32 + k4];
            o.x = f2bf(v.x); o.y = f2bf(v.y); o.z = f2bf(v.z); o.w = f2bf(v.w);
        }
        ((ushort4*)wih_pad)[u] = o;
    } else if (i < NA + NB + NC + ND) {
        const int u = i - NA - NB - NC;
        const int row = u >> 5, k0 = (u & 31) * 4;
        const int dir = row / 384, rem = row % 384, g = rem >> 7, j = rem & 127;
        ushort4 o = {0, 0, 0, 0};
        if (j < 100) {
            const float* w = dir ? whh_b : whh_f;   // [300][100]
            const float* wr = w + (g * 100 + j) * 100;
            unsigned short t[4];
            #pragma unroll
            for (int q = 0; q < 4; ++q)
                t[q] = (k0 + q < 100) ? f2bf(wr[k0 + q]) : (unsigned short)0;
            o.x = t[0]; o.y = t[1]; o.z = t[2]; o.w = t[3];
        }
        ((ushort4*)whh_pad)[u] = o;
    }
}

// ---------------------------------------------------------------------------
// K1: gather bf16 emb (all 512 threads) -> shfl-based tree aggregation ->
// bf16 A tile; B = Wc bf16. MFMA 16x16x32; epilogue: +cnt*bc, per-tree max,
// relu. Thread = (tree=tid>>6, ng=(lane>>4) node-group of 4, seg=lane&15).
// ---------------------------------------------------------------------------
__global__ __launch_bounds__(512) void k_encode(
    const int* __restrict__ tok1, const int* __restrict__ tok2,
    const unsigned short* __restrict__ emb_bf,
    const unsigned short* __restrict__ wc_bf,
    const float* __restrict__ bc,
    unsigned short* __restrict__ enc_bf)
{
    __shared__ unsigned short A_lds[128 * 128];   // [row][k] swizzled (32KB)
    __shared__ unsigned short B_lds[128 * 128];   // [col][k] swizzled (32KB)
    const int tid = threadIdx.x;
    const int blk = blockIdx.x;
    const int e = blk >> 10;
    const int tree0 = (blk & 1023) * 8;
    const int* __restrict__ tok = e ? tok2 : tok1;

    const int lane = tid & 63;
    const int tr  = tid >> 6;        // tree 0..7 (== wave)
    const int ng  = lane >> 4;       // node group: nodes ng*4..ng*4+3
    const int seg = lane & 15;       // 8-dim segment

    // stage Wc loads early (independent of token chain)
    u32x4 wcv[4];
    #pragma unroll
    for (int it = 0; it < 4; ++it) {
        const int idx = tid + 512 * it;          // 0..2047
        wcv[it] = *(const u32x4*)(wc_bf + (idx >> 4) * EE + (idx & 15) * 8);
    }

    // gather 4 emb rows (nodes ng*4..+3), 8 dims each
    const int tb = (tree0 + tr) * KN + ng * 4;
    const int tk0 = tok[tb + 0], tk1 = tok[tb + 1], tk2 = tok[tb + 2], tk3 = tok[tb + 3];
    f32x8 a0 = cvt8(*(const bf8*)(emb_bf + (size_t)tk0 * EE + seg * 8));
    f32x8 a1 = cvt8(*(const bf8*)(emb_bf + (size_t)tk1 * EE + seg * 8));
    f32x8 a2 = cvt8(*(const bf8*)(emb_bf + (size_t)tk2 * EE + seg * 8));
    f32x8 a3 = cvt8(*(const bf8*)(emb_bf + (size_t)tk3 * EE + seg * 8));

    // bottom-up child-sum via cross-lane shfl (node = ng*4 + local idx)
    {
        f32x8 t0 = shx(a3, 32);                    // ng1 <- ng3: a15
        if (ng == 1) a3 += t0;                     // a7 += a15
        f32x8 u1 = shx(a3, 16), u2 = shx(a0, 32);  // ng0<-ng1:a7 ; ng0<-ng2:a8
        if (ng == 0) a3 += u1 + u2;                // a3 += a7 + a8
        f32x8 v1 = shx(a1, 48), v2 = shx(a2, 48);  // ng1<-ng2: a9, a10
        if (ng == 1) a0 += v1 + v2;                // a4 += a9 + a10
        f32x8 w1 = shx(a3, 48), w2 = shx(a0, 32);  // ng1<-ng2:a11 ; ng1<-ng3:a12
        if (ng == 1) a1 += w1 + w2;                // a5 += a11 + a12
        f32x8 x1 = shx(a1, 32), x2 = shx(a2, 32);  // ng1<-ng3: a13, a14
        if (ng == 1) a2 += x1 + x2;                // a6 += a13 + a14
        f32x8 z1 = shx(a0, 16);                    // ng0<-ng1: a4
        if (ng == 0) a1 += a3 + z1;                // a1 += a3 + a4
        f32x8 z2 = shx(a1, 16), z3 = shx(a2, 16);  // ng0<-ng1: a5, a6
        if (ng == 0) a2 += z2 + z3;                // a2 += a5 + a6
        if (ng == 0) a0 += a1 + a2;                // a0 += a1 + a2
    }

    // write aggregated rows to A tile (rows = tr*16 + ng*4 + i)
    {
        const int r0 = tr * 16 + ng * 4;
        *(bf8*)((char*)A_lds + (r0+0) * 256 + SWZ(r0+0, seg * 16)) = pack8(a0);
        *(bf8*)((char*)A_lds + (r0+1) * 256 + SWZ(r0+1, seg * 16)) = pack8(a1);
        *(bf8*)((char*)A_lds + (r0+2) * 256 + SWZ(r0+2, seg * 16)) = pack8(a2);
        *(bf8*)((char*)A_lds + (r0+3) * 256 + SWZ(r0+3, seg * 16)) = pack8(a3);
    }
    #pragma unroll
    for (int it = 0; it < 4; ++it) {
        const int idx = tid + 512 * it;
        const int row = idx >> 4, sg = idx & 15;
        *(u32x4*)((char*)B_lds + row * 256 + SWZ(row, sg * 16)) = wcv[it];
    }
    __syncthreads();

    const int wid = tid >> 6;
    const int wr = wid >> 1, wc = wid & 1;
    const int l15 = lane & 15, lg = lane >> 4;

    f32x4 acc[2][4];
    #pragma unroll
    for (int rt = 0; rt < 2; ++rt)
        #pragma unroll
        for (int ct = 0; ct < 4; ++ct) acc[rt][ct] = (f32x4){0.f, 0.f, 0.f, 0.f};

    #pragma unroll
    for (int ks = 0; ks < 4; ++ks) {
        bf8 aF[2], bF[4];
        #pragma unroll
        for (int rt = 0; rt < 2; ++rt) {
            const int row = wr * 32 + rt * 16 + l15;
            aF[rt] = *(const bf8*)((const char*)A_lds + row * 256 + SWZ(row, ks * 64 + lg * 16));
        }
        #pragma unroll
        for (int ct = 0; ct < 4; ++ct) {
            const int col = wc * 64 + ct * 16 + l15;
            bF[ct] = *(const bf8*)((const char*)B_lds + col * 256 + SWZ(col, ks * 64 + lg * 16));
        }
        #pragma unroll
        for (int rt = 0; rt < 2; ++rt)
            #pragma unroll
            for (int ct = 0; ct < 4; ++ct)
                acc[rt][ct] = __builtin_amdgcn_mfma_f32_16x16x32_bf16(aF[rt], bF[ct], acc[rt][ct], 0, 0, 0);
    }

    #pragma unroll
    for (int rt = 0; rt < 2; ++rt) {
        const int ltree = wr * 2 + rt;
        #pragma unroll
        for (int ct = 0; ct < 4; ++ct) {
            const int col = wc * 64 + ct * 16 + l15;
            const float bcv = bc[col];
            f32x4 v = acc[rt][ct];
            float m = -1e30f;
            #pragma unroll
            for (int r = 0; r < 4; ++r)
                m = fmaxf(m, v[r] + c_cnt[lg * 4 + r] * bcv);
            m = fmaxf(m, __shfl_xor(m, 16));
            m = fmaxf(m, __shfl_xor(m, 32));
            m = fmaxf(m, 0.f);
            if (lg == 0) {
                const int gtree = tree0 + ltree;
                const int row = (gtree & 127) * 64 + (gtree >> 7);   // t*64 + b
                enc_bf[((size_t)e * NTREE + row) * EE + col] = f2bf(m);
            }
        }
    }
}

// ---------------------------------------------------------------------------
// K3: fused GRU scan. 16 blocks (e,dir,bgroup16) x 448 thr (7 waves).
// Raw s_barrier + writer-side lgkmcnt(0) ONLY (no vmcnt drain!) so the
// depth-2 enc prefetch floats across barriers with counted vmcnt waits.
// Shared accumulators for r,z gates (gi+gh in same acc tile).
// ---------------------------------------------------------------------------
__global__ __launch_bounds__(448, 2) void k_gru(
    const unsigned short* __restrict__ enc_bf,
    const unsigned short* __restrict__ wih_pad,
    const unsigned short* __restrict__ whh_pad,
    const float* __restrict__ bih_f, const float* __restrict__ bih_b,
    const float* __restrict__ bhh_f, const float* __restrict__ bhh_b,
    float* __restrict__ hmax_out)
{
    __shared__ unsigned short h_lds[2][16 * 128];   // [buf][b][k] swizzled, 8KB
    const int tid  = threadIdx.x;
    const int blk  = blockIdx.x;        // 16
    const int e    = blk >> 3;
    const int dir  = (blk >> 2) & 1;
    const int b0   = (blk & 3) * 16;
    const int w    = tid >> 6;
    const int lane = tid & 63;
    const int l15  = lane & 15;
    const int lg   = lane >> 4;
    const int jbase = w * 16;

    for (int u = tid; u < 512; u += 448)
        ((u32x4*)h_lds)[u] = (u32x4){0u, 0u, 0u, 0u};

    // weight fragments: A[j=jbase+l15][k=ks*32+lg*8 ..+8]
    bf8 aI[3][4], aH[3][4];
    {
        const unsigned short* wiP = wih_pad + (size_t)dir * 3 * 128 * 128;
        const unsigned short* whP = whh_pad + (size_t)dir * 3 * 128 * 128;
        #pragma unroll
        for (int g = 0; g < 3; ++g)
            #pragma unroll
            for (int ks = 0; ks < 4; ++ks) {
                const size_t ro = (size_t)(g * 128 + jbase + l15) * 128 + ks * 32 + lg * 8;
                aI[g][ks] = *(const bf8*)(wiP + ro);
                aH[g][ks] = *(const bf8*)(whP + ro);
            }
    }
    const float* __restrict__ bih = dir ? bih_b : bih_f;
    const float* __restrict__ bhh = dir ? bhh_b : bhh_f;
    float bsr[4], bsz[4], bin[4], bhn[4];
    #pragma unroll
    for (int r = 0; r < 4; ++r) {
        const int j = jbase + lg * 4 + r;
        bsr[r] = (j < 100) ? bih[j]       + bhh[j]       : 0.f;
        bsz[r] = (j < 100) ? bih[100 + j] + bhh[100 + j] : 0.f;
        bin[r] = (j < 100) ? bih[200 + j] : 0.f;
        bhn[r] = (j < 100) ? bhh[200 + j] : 0.f;
    }

    const unsigned short* encp =
        enc_bf + ((size_t)e * NTREE + b0 + l15) * EE + lg * 8;

    // depth-2 prefetch of enc B-fragments
    bf8 eA[4], eB[4];
    {
        const int tm0 = dir ? 127 : 0;
        const int tm1 = dir ? 126 : 1;
        #pragma unroll
        for (int ks = 0; ks < 4; ++ks) {
            eA[ks] = *(const bf8*)(encp + (size_t)tm0 * 8192 + ks * 32);
            eB[ks] = *(const bf8*)(encp + (size_t)tm1 * 8192 + ks * 32);
        }
    }

    float h_reg[4] = {0.f, 0.f, 0.f, 0.f};
    float hmx[4]   = {-1e30f, -1e30f, -1e30f, -1e30f};
    __syncthreads();

#define GRU_STEP(EF, P, PT)                                                    \
    {                                                                          \
        bf8 hF[4];                                                             \
        const char* hb = (const char*)h_lds + (P) * 4096 + l15 * 256;          \
        _Pragma("unroll")                                                      \
        for (int ks = 0; ks < 4; ++ks)                                         \
            hF[ks] = *(const bf8*)(hb + ((ks * 64 + lg * 16) ^ ((l15 & 7) << 4))); \
        f32x4 ar = (f32x4){0.f,0.f,0.f,0.f}, az = ar, ai = ar, ah = ar;        \
        _Pragma("unroll")                                                      \
        for (int ks = 0; ks < 4; ++ks) {                                       \
            ar = __builtin_amdgcn_mfma_f32_16x16x32_bf16(aI[0][ks], EF[ks], ar, 0, 0, 0); \
            az = __builtin_amdgcn_mfma_f32_16x16x32_bf16(aI[1][ks], EF[ks], az, 0, 0, 0); \
            ai = __builtin_amdgcn_mfma_f32_16x16x32_bf16(aI[2][ks], EF[ks], ai, 0, 0, 0); \
        }                                                                      \
        if ((PT) < S_) {                                                       \
            const int tmn = dir ? (127 - (PT)) : (PT);                         \
            _Pragma("unroll")                                                  \
            for (int ks = 0; ks < 4; ++ks)                                     \
                EF[ks] = *(const bf8*)(encp + (size_t)tmn * 8192 + ks * 32);   \
        }                                                                      \
        _Pragma("unroll")                                                      \
        for (int ks = 0; ks < 4; ++ks) {                                       \
            ar = __builtin_amdgcn_mfma_f32_16x16x32_bf16(aH[0][ks], hF[ks], ar, 0, 0, 0); \
            az = __builtin_amdgcn_mfma_f32_16x16x32_bf16(aH[1][ks], hF[ks], az, 0, 0, 0); \
            ah = __builtin_amdgcn_mfma_f32_16x16x32_bf16(aH[2][ks], hF[ks], ah, 0, 0, 0); \
        }                                                                      \
        unsigned short hq[4];                                                  \
        _Pragma("unroll")                                                      \
        for (int r = 0; r < 4; ++r) {                                          \
            const float xr  = ar[r] + bsr[r];                                  \
            const float xz  = az[r] + bsz[r];                                  \
            const float in_ = ai[r] + bin[r];                                  \
            const float hn  = ah[r] + bhn[r];                                  \
            const float rg  = __builtin_amdgcn_rcpf(1.f + __expf(-xr));        \
            const float zg  = __builtin_amdgcn_rcpf(1.f + __expf(-xz));        \
            float nx = in_ + rg * hn;                                          \
            nx = fminf(fmaxf(nx, -15.f), 15.f);                                \
            const float ng = 1.f - 2.f * __builtin_amdgcn_rcpf(__expf(2.f * nx) + 1.f); \
            float hnew = ng + zg * (h_reg[r] - ng);                            \
            if (jbase + lg * 4 + r >= 100) hnew = 0.f;                         \
            h_reg[r] = hnew;                                                   \
            hmx[r] = fmaxf(hmx[r], hnew);                                      \
            hq[r] = f2bf(hnew);                                                \
        }                                                                      \
        {                                                                      \
            const int o  = (jbase + lg * 4) * 2;                               \
            const int so = ((o & ~15) ^ ((l15 & 7) << 4)) | (o & 15);          \
            ushort4 hv; hv.x = hq[0]; hv.y = hq[1]; hv.z = hq[2]; hv.w = hq[3];\
            *(ushort4*)((char*)h_lds + ((P) ^ 1) * 4096 + l15 * 256 + so) = hv;\
        }                                                                      \
        asm volatile("s_waitcnt lgkmcnt(0)" ::: "memory");                     \
        __builtin_amdgcn_s_barrier();                                          \
        __builtin_amdgcn_sched_barrier(0);                                     \
    }

    for (int t = 0; t < S_; t += 2) {
        GRU_STEP(eA, 0, t + 2)
        GRU_STEP(eB, 1, t + 3)
    }
#undef GRU_STEP

    #pragma unroll
    for (int r = 0; r < 4; ++r) {
        const int j = jbase + lg * 4 + r;
        if (j < 100)
            hmax_out[((size_t)((e * 2 + dir) * 64 + b0 + l15)) * HH + j] = hmx[r];
    }
}

// ---------------------------------------------------------------------------
// K4: fc + softmax
// ---------------------------------------------------------------------------
__global__ void k_final(const float* __restrict__ hmax,
                        const float* __restrict__ fcw,
                        const float* __restrict__ fcb,
                        float* __restrict__ out)
{
    const int b = threadIdx.x;
    if (b >= B_) return;
    float y0 = fcb[0], y1 = fcb[1];
    for (int m = 0; m < 400; ++m) {
        const int e   = m / 200;
        const int dm  = m % 200;
        const int dir = dm / 100;
        const int j   = dm % 100;
        const float x = hmax[((size_t)((e * 2 + dir) * 64 + b)) * HH + j];
        y0 += fcw[m]       * x;
        y1 += fcw[400 + m] * x;
    }
    const float mx = fmaxf(y0, y1);
    const float e0 = __expf(y0 - mx), e1 = __expf(y1 - mx);
    const float s = e0 + e1;
    out[b * 2]     = e0 / s;
    out[b * 2 + 1] = e1 / s;
}

extern "C" void kernel_launch(void* const* d_in, const int* in_sizes, int n_in,
                              void* d_out, int out_size, void* d_ws, size_t ws_size,
                              hipStream_t stream)
{
    const int*   tok1  = (const int*)d_in[0];
    const int*   tok2  = (const int*)d_in[1];
    const float* emb   = (const float*)d_in[4];
    const float* Wc    = (const float*)d_in[5];
    const float* bc    = (const float*)d_in[6];
    const float* wih_f = (const float*)d_in[7];
    const float* whh_f = (const float*)d_in[8];
    const float* bih_f = (const float*)d_in[9];
    const float* bhh_f = (const float*)d_in[10];
    const float* wih_b = (const float*)d_in[11];
    const float* whh_b = (const float*)d_in[12];
    const float* bih_b = (const float*)d_in[13];
    const float* bhh_b = (const float*)d_in[14];
    const float* fcw   = (const float*)d_in[15];
    const float* fcb   = (const float*)d_in[16];

    char* ws = (char*)d_ws;
    unsigned short* emb_bf  = (unsigned short*)(ws + EMB_BF_OFF);
    unsigned short* wc_bf   = (unsigned short*)(ws + WC_BF_OFF);
    unsigned short* wih_pad = (unsigned short*)(ws + WIH_BF_OFF);
    unsigned short* whh_pad = (unsigned short*)(ws + WHH_BF_OFF);
    unsigned short* enc_bf  = (unsigned short*)(ws + ENC_BF_OFF);
    float*          hmax    = (float*)(ws + HMAX_OFF);

    k_prep<<<6458, 256, 0, stream>>>(emb, Wc, wih_f, wih_b, whh_f, whh_b,
                                     emb_bf, wc_bf, wih_pad, whh_pad);
    k_encode<<<2048, 512, 0, stream>>>(tok1, tok2, emb_bf, wc_bf, bc, enc_bf);
    k_gru<<<16, 448, 0, stream>>>(enc_bf, wih_pad, whh_pad,
                                  bih_f, bih_b, bhh_f, bhh_b, hmax);
    k_final<<<1, 64, 0, stream>>>(hmax, fcw, fcb, (float*)d_out);
}

// Round 6
// 188.516 us; speedup vs baseline: 1.8092x; 1.0189x over previous
//
#include <hip/hip_runtime.h>
#include <math.h>

#define B_      64
#define S_      128
#define KN      16
#define EE      128
#define HH      100
#define NTREE   8192            // B_*S_

typedef __attribute__((ext_vector_type(8))) short   bf8;    // 8 bf16 (4 VGPRs)
typedef __attribute__((ext_vector_type(4))) float   f32x4;
typedef __attribute__((ext_vector_type(8))) float   f32x8;
typedef __attribute__((ext_vector_type(4))) unsigned int u32x4;

// workspace byte offsets (256-aligned)
#define EMB_BF_OFF   0u           // 50000*128*2 = 12,800,000
#define WC_BF_OFF    12800000u    // 128*128*2   = 32,768
#define WIH_BF_OFF   12832768u    // 768*128*2   = 196,608 (padded [dir][g][128j][128k])
#define WHH_BF_OFF   13029376u    // 768*128*2   = 196,608 (padded, zero pads)
#define ENC_BF_OFF   13225984u    // 16384*128*2 = 4,194,304   rows = e*8192 + t*64 + b
#define HMAX_OFF     17420288u    // 25600*4     = 102,400

__constant__ float c_cnt[16] = {16.f,8.f,7.f,4.f,3.f,3.f,3.f,2.f,
                                1.f,1.f,1.f,1.f,1.f,1.f,1.f,1.f};

__device__ __forceinline__ float bf2f(unsigned short u) {
    unsigned int x = ((unsigned int)u) << 16;
    return __builtin_bit_cast(float, x);
}
__device__ __forceinline__ unsigned short f2bf(float f) {
    unsigned int x = __builtin_bit_cast(unsigned int, f);
    x = x + 0x7fffu + ((x >> 16) & 1u);          // RNE
    return (unsigned short)(x >> 16);
}
__device__ __forceinline__ f32x8 cvt8(const bf8& v) {
    f32x8 f;
    #pragma unroll
    for (int q = 0; q < 8; ++q) f[q] = bf2f((unsigned short)v[q]);
    return f;
}
__device__ __forceinline__ f32x8 shx(const f32x8& v, int m) {
    f32x8 o;
    #pragma unroll
    for (int q = 0; q < 8; ++q) o[q] = __shfl_xor(v[q], m);
    return o;
}
__device__ __forceinline__ bf8 pack8(const f32x8& v) {
    bf8 o;
    #pragma unroll
    for (int q = 0; q < 8; ++q) o[q] = (short)f2bf(v[q]);
    return o;
}
// swizzle a 16B-aligned column-byte offset within a 256B row
#define SWZ(row, cb) ((cb) ^ (((row) & 7) << 4))

// ---------------------------------------------------------------------------
// K0: fp32 -> bf16 prep: emb, Wc, wih padded [2][3][128][128], whh padded same
// ---------------------------------------------------------------------------
#define NA 1600000   // emb float4s
#define NB 4096      // Wc float4s
#define NC 24576     // wih_pad ushort4s (768*128/4)
#define ND 24576     // whh_pad ushort4s
__global__ __launch_bounds__(256) void k_prep(
    const float* __restrict__ emb, const float* __restrict__ Wc,
    const float* __restrict__ wih_f, const float* __restrict__ wih_b,
    const float* __restrict__ whh_f, const float* __restrict__ whh_b,
    unsigned short* __restrict__ emb_bf, unsigned short* __restrict__ wc_bf,
    unsigned short* __restrict__ wih_pad, unsigned short* __restrict__ whh_pad)
{
    const int i = blockIdx.x * 256 + threadIdx.x;
    if (i < NA + NB) {
        const float* src = (i < NA) ? emb : Wc;
        unsigned short* dst = (i < NA) ? emb_bf : wc_bf;
        const int j = (i < NA) ? i : i - NA;
        float4 v = ((const float4*)src)[j];
        ushort4 o;
        o.x = f2bf(v.x); o.y = f2bf(v.y); o.z = f2bf(v.z); o.w = f2bf(v.w);
        ((ushort4*)dst)[j] = o;
    } else if (i < NA + NB + NC) {
        const int u = i - NA - NB;                  // 0..24575
        const int row = u >> 5, k4 = u & 31;        // row 0..767
        const int dir = row / 384, rem = row % 384, g = rem >> 7, j = rem & 127;
        ushort4 o = {0, 0, 0, 0};
        if (j < 100) {
            const float* w = dir ? wih_b : wih_f;   // [300][128]
            float4 v = ((const float4*)w)[(g * 100 + j) * 32 + k4];
            o.x = f2bf(v.x); o.y = f2bf(v.y); o.z = f2bf(v.z); o.w = f2bf(v.w);
        }
        ((ushort4*)wih_pad)[u] = o;
    } else if (i < NA + NB + NC + ND) {
        const int u = i - NA - NB - NC;
        const int row = u >> 5, k0 = (u & 31) * 4;
        const int dir = row / 384, rem = row % 384, g = rem >> 7, j = rem & 127;
        ushort4 o = {0, 0, 0, 0};
        if (j < 100) {
            const float* w = dir ? whh_b : whh_f;   // [300][100]
            const float* wr = w + (g * 100 + j) * 100;
            unsigned short t[4];
            #pragma unroll
            for (int q = 0; q < 4; ++q)
                t[q] = (k0 + q < 100) ? f2bf(wr[k0 + q]) : (unsigned short)0;
            o.x = t[0]; o.y = t[1]; o.z = t[2]; o.w = t[3];
        }
        ((ushort4*)whh_pad)[u] = o;
    }
}

// ---------------------------------------------------------------------------
// K1: gather bf16 emb (all 512 threads) -> shfl-based tree aggregation ->
// bf16 A tile; B = Wc bf16. MFMA 16x16x32; epilogue: +cnt*bc, per-tree max,
// relu. Thread = (tree=tid>>6, ng=(lane>>4) node-group of 4, seg=lane&15).
// ---------------------------------------------------------------------------
__global__ __launch_bounds__(512) void k_encode(
    const int* __restrict__ tok1, const int* __restrict__ tok2,
    const unsigned short* __restrict__ emb_bf,
    const unsigned short* __restrict__ wc_bf,
    const float* __restrict__ bc,
    unsigned short* __restrict__ enc_bf)
{
    __shared__ unsigned short A_lds[128 * 128];   // [row][k] swizzled (32KB)
    __shared__ unsigned short B_lds[128 * 128];   // [col][k] swizzled (32KB)
    const int tid = threadIdx.x;
    const int blk = blockIdx.x;
    const int e = blk >> 10;
    const int tree0 = (blk & 1023) * 8;
    const int* __restrict__ tok = e ? tok2 : tok1;

    const int lane = tid & 63;
    const int tr  = tid >> 6;        // tree 0..7 (== wave)
    const int ng  = lane >> 4;       // node group: nodes ng*4..ng*4+3
    const int seg = lane & 15;       // 8-dim segment

    // stage Wc loads early (independent of token chain)
    u32x4 wcv[4];
    #pragma unroll
    for (int it = 0; it < 4; ++it) {
        const int idx = tid + 512 * it;          // 0..2047
        wcv[it] = *(const u32x4*)(wc_bf + (idx >> 4) * EE + (idx & 15) * 8);
    }

    // gather 4 emb rows (nodes ng*4..+3), 8 dims each
    const int tb = (tree0 + tr) * KN + ng * 4;
    const int tk0 = tok[tb + 0], tk1 = tok[tb + 1], tk2 = tok[tb + 2], tk3 = tok[tb + 3];
    f32x8 a0 = cvt8(*(const bf8*)(emb_bf + (size_t)tk0 * EE + seg * 8));
    f32x8 a1 = cvt8(*(const bf8*)(emb_bf + (size_t)tk1 * EE + seg * 8));
    f32x8 a2 = cvt8(*(const bf8*)(emb_bf + (size_t)tk2 * EE + seg * 8));
    f32x8 a3 = cvt8(*(const bf8*)(emb_bf + (size_t)tk3 * EE + seg * 8));

    // bottom-up child-sum via cross-lane shfl (node = ng*4 + local idx)
    {
        f32x8 t0 = shx(a3, 32);                    // ng1 <- ng3: a15
        if (ng == 1) a3 += t0;                     // a7 += a15
        f32x8 u1 = shx(a3, 16), u2 = shx(a0, 32);  // ng0<-ng1:a7 ; ng0<-ng2:a8
        if (ng == 0) a3 += u1 + u2;                // a3 += a7 + a8
        f32x8 v1 = shx(a1, 48), v2 = shx(a2, 48);  // ng1<-ng2: a9, a10
        if (ng == 1) a0 += v1 + v2;                // a4 += a9 + a10
        f32x8 w1 = shx(a3, 48), w2 = shx(a0, 32);  // ng1<-ng2:a11 ; ng1<-ng3:a12
        if (ng == 1) a1 += w1 + w2;                // a5 += a11 + a12
        f32x8 x1 = shx(a1, 32), x2 = shx(a2, 32);  // ng1<-ng3: a13, a14
        if (ng == 1) a2 += x1 + x2;                // a6 += a13 + a14
        f32x8 z1 = shx(a0, 16);                    // ng0<-ng1: a4
        if (ng == 0) a1 += a3 + z1;                // a1 += a3 + a4
        f32x8 z2 = shx(a1, 16), z3 = shx(a2, 16);  // ng0<-ng1: a5, a6
        if (ng == 0) a2 += z2 + z3;                // a2 += a5 + a6
        if (ng == 0) a0 += a1 + a2;                // a0 += a1 + a2
    }

    // write aggregated rows to A tile (rows = tr*16 + ng*4 + i)
    {
        const int r0 = tr * 16 + ng * 4;
        *(bf8*)((char*)A_lds + (r0+0) * 256 + SWZ(r0+0, seg * 16)) = pack8(a0);
        *(bf8*)((char*)A_lds + (r0+1) * 256 + SWZ(r0+1, seg * 16)) = pack8(a1);
        *(bf8*)((char*)A_lds + (r0+2) * 256 + SWZ(r0+2, seg * 16)) = pack8(a2);
        *(bf8*)((char*)A_lds + (r0+3) * 256 + SWZ(r0+3, seg * 16)) = pack8(a3);
    }
    #pragma unroll
    for (int it = 0; it < 4; ++it) {
        const int idx = tid + 512 * it;
        const int row = idx >> 4, sg = idx & 15;
        *(u32x4*)((char*)B_lds + row * 256 + SWZ(row, sg * 16)) = wcv[it];
    }
    __syncthreads();

    const int wid = tid >> 6;
    const int wr = wid >> 1, wc = wid & 1;
    const int l15 = lane & 15, lg = lane >> 4;

    f32x4 acc[2][4];
    #pragma unroll
    for (int rt = 0; rt < 2; ++rt)
        #pragma unroll
        for (int ct = 0; ct < 4; ++ct) acc[rt][ct] = (f32x4){0.f, 0.f, 0.f, 0.f};

    #pragma unroll
    for (int ks = 0; ks < 4; ++ks) {
        bf8 aF[2], bF[4];
        #pragma unroll
        for (int rt = 0; rt < 2; ++rt) {
            const int row = wr * 32 + rt * 16 + l15;
            aF[rt] = *(const bf8*)((const char*)A_lds + row * 256 + SWZ(row, ks * 64 + lg * 16));
        }
        #pragma unroll
        for (int ct = 0; ct < 4; ++ct) {
            const int col = wc * 64 + ct * 16 + l15;
            bF[ct] = *(const bf8*)((const char*)B_lds + col * 256 + SWZ(col, ks * 64 + lg * 16));
        }
        #pragma unroll
        for (int rt = 0; rt < 2; ++rt)
            #pragma unroll
            for (int ct = 0; ct < 4; ++ct)
                acc[rt][ct] = __builtin_amdgcn_mfma_f32_16x16x32_bf16(aF[rt], bF[ct], acc[rt][ct], 0, 0, 0);
    }

    #pragma unroll
    for (int rt = 0; rt < 2; ++rt) {
        const int ltree = wr * 2 + rt;
        #pragma unroll
        for (int ct = 0; ct < 4; ++ct) {
            const int col = wc * 64 + ct * 16 + l15;
            const float bcv = bc[col];
            f32x4 v = acc[rt][ct];
            float m = -1e30f;
            #pragma unroll
            for (int r = 0; r < 4; ++r)
                m = fmaxf(m, v[r] + c_cnt[lg * 4 + r] * bcv);
            m = fmaxf(m, __shfl_xor(m, 16));
            m = fmaxf(m, __shfl_xor(m, 32));
            m = fmaxf(m, 0.f);
            if (lg == 0) {
                const int gtree = tree0 + ltree;
                const int row = (gtree & 127) * 64 + (gtree >> 7);   // t*64 + b
                enc_bf[((size_t)e * NTREE + row) * EE + col] = f2bf(m);
            }
        }
    }
}

// ---------------------------------------------------------------------------
// K3: fused GRU scan. 16 blocks (e,dir,bgroup16) x 448 thr (7 waves).
// waves_per_eu(2,2): register budget 256 so the 24 weight fragments stay
// RESIDENT (R5's VGPR=100 showed the compiler re-loading them every step).
// Raw s_barrier + writer-side lgkmcnt(0) only (no vmcnt drain).
// Gates: exp2-folded sigmoid/tanh, no clamp (inf-safe), pad self-zeroing.
// ---------------------------------------------------------------------------
__global__ __attribute__((amdgpu_waves_per_eu(2, 2))) __launch_bounds__(448)
void k_gru(
    const unsigned short* __restrict__ enc_bf,
    const unsigned short* __restrict__ wih_pad,
    const unsigned short* __restrict__ whh_pad,
    const float* __restrict__ bih_f, const float* __restrict__ bih_b,
    const float* __restrict__ bhh_f, const float* __restrict__ bhh_b,
    float* __restrict__ hmax_out)
{
    __shared__ unsigned short h_lds[2][16 * 128];   // [buf][b][k] swizzled, 8KB
    const int tid  = threadIdx.x;
    const int blk  = blockIdx.x;        // 16
    const int e    = blk >> 3;
    const int dir  = (blk >> 2) & 1;
    const int b0   = (blk & 3) * 16;
    const int w    = tid >> 6;
    const int lane = tid & 63;
    const int l15  = lane & 15;
    const int lg   = lane >> 4;
    const int jbase = w * 16;

    for (int u = tid; u < 512; u += 448)
        ((u32x4*)h_lds)[u] = (u32x4){0u, 0u, 0u, 0u};

    // weight fragments: A[j=jbase+l15][k=ks*32+lg*8 ..+8] — keep RESIDENT
    bf8 aI[3][4], aH[3][4];
    {
        const unsigned short* wiP = wih_pad + (size_t)dir * 3 * 128 * 128;
        const unsigned short* whP = whh_pad + (size_t)dir * 3 * 128 * 128;
        #pragma unroll
        for (int g = 0; g < 3; ++g)
            #pragma unroll
            for (int ks = 0; ks < 4; ++ks) {
                const size_t ro = (size_t)(g * 128 + jbase + l15) * 128 + ks * 32 + lg * 8;
                aI[g][ks] = *(const bf8*)(wiP + ro);
                aH[g][ks] = *(const bf8*)(whP + ro);
                asm volatile("" : "+v"(aI[g][ks]));
                asm volatile("" : "+v"(aH[g][ks]));
            }
    }
    const float* __restrict__ bih = dir ? bih_b : bih_f;
    const float* __restrict__ bhh = dir ? bhh_b : bhh_f;
    float bsr[4], bsz[4], bin[4], bhn[4];
    #pragma unroll
    for (int r = 0; r < 4; ++r) {
        const int j = jbase + lg * 4 + r;
        bsr[r] = (j < 100) ? bih[j]       + bhh[j]       : 0.f;
        bsz[r] = (j < 100) ? bih[100 + j] + bhh[100 + j] : 0.f;
        bin[r] = (j < 100) ? bih[200 + j] : 0.f;
        bhn[r] = (j < 100) ? bhh[200 + j] : 0.f;
    }

    const unsigned short* encp =
        enc_bf + ((size_t)e * NTREE + b0 + l15) * EE + lg * 8;

    // depth-2 prefetch of enc B-fragments
    bf8 eA[4], eB[4];
    {
        const int tm0 = dir ? 127 : 0;
        const int tm1 = dir ? 126 : 1;
        #pragma unroll
        for (int ks = 0; ks < 4; ++ks) {
            eA[ks] = *(const bf8*)(encp + (size_t)tm0 * 8192 + ks * 32);
            eB[ks] = *(const bf8*)(encp + (size_t)tm1 * 8192 + ks * 32);
        }
    }

    float h_reg[4] = {0.f, 0.f, 0.f, 0.f};
    float hmx[4]   = {-1e30f, -1e30f, -1e30f, -1e30f};
    __syncthreads();

#define L2E  1.4426950408889634f
#define GRU_STEP(EF, P, PT)                                                    \
    {                                                                          \
        bf8 hF[4];                                                             \
        const char* hb = (const char*)h_lds + (P) * 4096 + l15 * 256;          \
        _Pragma("unroll")                                                      \
        for (int ks = 0; ks < 4; ++ks)                                         \
            hF[ks] = *(const bf8*)(hb + ((ks * 64 + lg * 16) ^ ((l15 & 7) << 4))); \
        f32x4 ar = (f32x4){0.f,0.f,0.f,0.f}, az = ar, ai = ar, ah = ar;        \
        _Pragma("unroll")                                                      \
        for (int ks = 0; ks < 4; ++ks) {                                       \
            ar = __builtin_amdgcn_mfma_f32_16x16x32_bf16(aI[0][ks], EF[ks], ar, 0, 0, 0); \
            az = __builtin_amdgcn_mfma_f32_16x16x32_bf16(aI[1][ks], EF[ks], az, 0, 0, 0); \
            ai = __builtin_amdgcn_mfma_f32_16x16x32_bf16(aI[2][ks], EF[ks], ai, 0, 0, 0); \
        }                                                                      \
        if ((PT) < S_) {                                                       \
            const int tmn = dir ? (127 - (PT)) : (PT);                         \
            _Pragma("unroll")                                                  \
            for (int ks = 0; ks < 4; ++ks)                                     \
                EF[ks] = *(const bf8*)(encp + (size_t)tmn * 8192 + ks * 32);   \
        }                                                                      \
        _Pragma("unroll")                                                      \
        for (int ks = 0; ks < 4; ++ks) {                                       \
            ar = __builtin_amdgcn_mfma_f32_16x16x32_bf16(aH[0][ks], hF[ks], ar, 0, 0, 0); \
            az = __builtin_amdgcn_mfma_f32_16x16x32_bf16(aH[1][ks], hF[ks], az, 0, 0, 0); \
            ah = __builtin_amdgcn_mfma_f32_16x16x32_bf16(aH[2][ks], hF[ks], ah, 0, 0, 0); \
        }                                                                      \
        unsigned short hq[4];                                                  \
        _Pragma("unroll")                                                      \
        for (int r = 0; r < 4; ++r) {                                          \
            const float xr  = ar[r] + bsr[r];                                  \
            const float xz  = az[r] + bsz[r];                                  \
            const float in_ = ai[r] + bin[r];                                  \
            const float hn  = ah[r] + bhn[r];                                  \
            const float rg  = __builtin_amdgcn_rcpf(1.f + __builtin_amdgcn_exp2f(-L2E * xr)); \
            const float zg  = __builtin_amdgcn_rcpf(1.f + __builtin_amdgcn_exp2f(-L2E * xz)); \
            const float nx  = in_ + rg * hn;                                   \
            const float ng  = 1.f - 2.f * __builtin_amdgcn_rcpf(1.f + __builtin_amdgcn_exp2f((2.f * L2E) * nx)); \
            const float hnew = ng + zg * (h_reg[r] - ng);                      \
            h_reg[r] = hnew;                                                   \
            hmx[r] = fmaxf(hmx[r], hnew);                                      \
            hq[r] = f2bf(hnew);                                                \
        }                                                                      \
        {                                                                      \
            const int o  = (jbase + lg * 4) * 2;                               \
            const int so = ((o & ~15) ^ ((l15 & 7) << 4)) | (o & 15);          \
            ushort4 hv; hv.x = hq[0]; hv.y = hq[1]; hv.z = hq[2]; hv.w = hq[3];\
            *(ushort4*)((char*)h_lds + ((P) ^ 1) * 4096 + l15 * 256 + so) = hv;\
        }                                                                      \
        asm volatile("s_waitcnt lgkmcnt(0)" ::: "memory");                     \
        __builtin_amdgcn_s_barrier();                                          \
        __builtin_amdgcn_sched_barrier(0);                                     \
    }

    for (int t = 0; t < S_; t += 2) {
        GRU_STEP(eA, 0, t + 2)
        GRU_STEP(eB, 1, t + 3)
    }
#undef GRU_STEP

    #pragma unroll
    for (int r = 0; r < 4; ++r) {
        const int j = jbase + lg * 4 + r;
        if (j < 100)
            hmax_out[((size_t)((e * 2 + dir) * 64 + b0 + l15)) * HH + j] = hmx[r];
    }
}

// ---------------------------------------------------------------------------
// K4: fc + softmax
// ---------------------------------------------------------------------------
__global__ void k_final(const float* __restrict__ hmax,
                        const float* __restrict__ fcw,
                        const float* __restrict__ fcb,
                        float* __restrict__ out)
{
    const int b = threadIdx.x;
    if (b >= B_) return;
    float y0 = fcb[0], y1 = fcb[1];
    for (int m = 0; m < 400; ++m) {
        const int e   = m / 200;
        const int dm  = m % 200;
        const int dir = dm / 100;
        const int j   = dm % 100;
        const float x = hmax[((size_t)((e * 2 + dir) * 64 + b)) * HH + j];
        y0 += fcw[m]       * x;
        y1 += fcw[400 + m] * x;
    }
    const float mx = fmaxf(y0, y1);
    const float e0 = __expf(y0 - mx), e1 = __expf(y1 - mx);
    const float s = e0 + e1;
    out[b * 2]     = e0 / s;
    out[b * 2 + 1] = e1 / s;
}

extern "C" void kernel_launch(void* const* d_in, const int* in_sizes, int n_in,
                              void* d_out, int out_size, void* d_ws, size_t ws_size,
                              hipStream_t stream)
{
    const int*   tok1  = (const int*)d_in[0];
    const int*   tok2  = (const int*)d_in[1];
    const float* emb   = (const float*)d_in[4];
    const float* Wc    = (const float*)d_in[5];
    const float* bc    = (const float*)d_in[6];
    const float* wih_f = (const float*)d_in[7];
    const float* whh_f = (const float*)d_in[8];
    const float* bih_f = (const float*)d_in[9];
    const float* bhh_f = (const float*)d_in[10];
    const float* wih_b = (const float*)d_in[11];
    const float* whh_b = (const float*)d_in[12];
    const float* bih_b = (const float*)d_in[13];
    const float* bhh_b = (const float*)d_in[14];
    const float* fcw   = (const float*)d_in[15];
    const float* fcb   = (const float*)d_in[16];

    char* ws = (char*)d_ws;
    unsigned short* emb_bf  = (unsigned short*)(ws + EMB_BF_OFF);
    unsigned short* wc_bf   = (unsigned short*)(ws + WC_BF_OFF);
    unsigned short* wih_pad = (unsigned short*)(ws + WIH_BF_OFF);
    unsigned short* whh_pad = (unsigned short*)(ws + WHH_BF_OFF);
    unsigned short* enc_bf  = (unsigned short*)(ws + ENC_BF_OFF);
    float*          hmax    = (float*)(ws + HMAX_OFF);

    k_prep<<<6458, 256, 0, stream>>>(emb, Wc, wih_f, wih_b, whh_f, whh_b,
                                     emb_bf, wc_bf, wih_pad, whh_pad);
    k_encode<<<2048, 512, 0, stream>>>(tok1, tok2, emb_bf, wc_bf, bc, enc_bf);
    k_gru<<<16, 448, 0, stream>>>(enc_bf, wih_pad, whh_pad,
                                  bih_f, bih_b, bhh_f, bhh_b, hmax);
    k_final<<<1, 64, 0, stream>>>(hmax, fcw, fcb, (float*)d_out);
}

// Round 7
// 187.940 us; speedup vs baseline: 1.8147x; 1.0031x over previous
//
#include <hip/hip_runtime.h>
#include <math.h>

#define B_      64
#define S_      128
#define KN      16
#define EE      128
#define HH      100
#define NTREE   8192            // B_*S_

typedef __attribute__((ext_vector_type(8))) short   bf8;    // 8 bf16 (4 VGPRs)
typedef __attribute__((ext_vector_type(4))) float   f32x4;
typedef __attribute__((ext_vector_type(8))) float   f32x8;
typedef __attribute__((ext_vector_type(4))) unsigned int u32x4;

// workspace byte offsets (256-aligned)
#define EMB_BF_OFF   0u           // 50000*128*2 = 12,800,000
#define WC_BF_OFF    12800000u    // 128*128*2   = 32,768
#define WIH_BF_OFF   12832768u    // 768*128*2   = 196,608 (padded [dir][g][128j][128k])
#define WHH_BF_OFF   13029376u    // 768*128*2   = 196,608 (padded, zero pads)
#define ENC_BF_OFF   13225984u    // 16384*128*2 = 4,194,304   rows = e*8192 + t*64 + b
#define HMAX_OFF     17420288u    // 25600*4     = 102,400

__constant__ float c_cnt[16] = {16.f,8.f,7.f,4.f,3.f,3.f,3.f,2.f,
                                1.f,1.f,1.f,1.f,1.f,1.f,1.f,1.f};

__device__ __forceinline__ float bf2f(unsigned short u) {
    unsigned int x = ((unsigned int)u) << 16;
    return __builtin_bit_cast(float, x);
}
__device__ __forceinline__ unsigned short f2bf(float f) {
    unsigned int x = __builtin_bit_cast(unsigned int, f);
    x = x + 0x7fffu + ((x >> 16) & 1u);          // RNE
    return (unsigned short)(x >> 16);
}
__device__ __forceinline__ f32x8 cvt8(const bf8& v) {
    f32x8 f;
    #pragma unroll
    for (int q = 0; q < 8; ++q) f[q] = bf2f((unsigned short)v[q]);
    return f;
}
__device__ __forceinline__ f32x8 shx(const f32x8& v, int m) {
    f32x8 o;
    #pragma unroll
    for (int q = 0; q < 8; ++q) o[q] = __shfl_xor(v[q], m);
    return o;
}
__device__ __forceinline__ bf8 pack8(const f32x8& v) {
    bf8 o;
    #pragma unroll
    for (int q = 0; q < 8; ++q) o[q] = (short)f2bf(v[q]);
    return o;
}
// swizzle a 16B-aligned column-byte offset within a 256B row
#define SWZ(row, cb) ((cb) ^ (((row) & 7) << 4))

// ---------------------------------------------------------------------------
// K0: fp32 -> bf16 prep: emb, Wc, wih padded [2][3][128][128], whh padded same
// ---------------------------------------------------------------------------
#define NA 1600000   // emb float4s
#define NB 4096      // Wc float4s
#define NC 24576     // wih_pad ushort4s (768*128/4)
#define ND 24576     // whh_pad ushort4s
__global__ __launch_bounds__(256) void k_prep(
    const float* __restrict__ emb, const float* __restrict__ Wc,
    const float* __restrict__ wih_f, const float* __restrict__ wih_b,
    const float* __restrict__ whh_f, const float* __restrict__ whh_b,
    unsigned short* __restrict__ emb_bf, unsigned short* __restrict__ wc_bf,
    unsigned short* __restrict__ wih_pad, unsigned short* __restrict__ whh_pad)
{
    const int i = blockIdx.x * 256 + threadIdx.x;
    if (i < NA + NB) {
        const float* src = (i < NA) ? emb : Wc;
        unsigned short* dst = (i < NA) ? emb_bf : wc_bf;
        const int j = (i < NA) ? i : i - NA;
        float4 v = ((const float4*)src)[j];
        ushort4 o;
        o.x = f2bf(v.x); o.y = f2bf(v.y); o.z = f2bf(v.z); o.w = f2bf(v.w);
        ((ushort4*)dst)[j] = o;
    } else if (i < NA + NB + NC) {
        const int u = i - NA - NB;                  // 0..24575
        const int row = u >> 5, k4 = u & 31;        // row 0..767
        const int dir = row / 384, rem = row % 384, g = rem >> 7, j = rem & 127;
        ushort4 o = {0, 0, 0, 0};
        if (j < 100) {
            const float* w = dir ? wih_b : wih_f;   // [300][128]
            float4 v = ((const float4*)w)[(g * 100 + j) * 32 + k4];
            o.x = f2bf(v.x); o.y = f2bf(v.y); o.z = f2bf(v.z); o.w = f2bf(v.w);
        }
        ((ushort4*)wih_pad)[u] = o;
    } else if (i < NA + NB + NC + ND) {
        const int u = i - NA - NB - NC;
        const int row = u >> 5, k0 = (u & 31) * 4;
        const int dir = row / 384, rem = row % 384, g = rem >> 7, j = rem & 127;
        ushort4 o = {0, 0, 0, 0};
        if (j < 100) {
            const float* w = dir ? whh_b : whh_f;   // [300][100]
            const float* wr = w + (g * 100 + j) * 100;
            unsigned short t[4];
            #pragma unroll
            for (int q = 0; q < 4; ++q)
                t[q] = (k0 + q < 100) ? f2bf(wr[k0 + q]) : (unsigned short)0;
            o.x = t[0]; o.y = t[1]; o.z = t[2]; o.w = t[3];
        }
        ((ushort4*)whh_pad)[u] = o;
    }
}

// ---------------------------------------------------------------------------
// K1: gather bf16 emb (all 512 threads) -> shfl-based tree aggregation ->
// bf16 A tile; B = Wc bf16. MFMA 16x16x32; epilogue: +cnt*bc, per-tree max,
// relu. (unchanged from R6)
// ---------------------------------------------------------------------------
__global__ __launch_bounds__(512) void k_encode(
    const int* __restrict__ tok1, const int* __restrict__ tok2,
    const unsigned short* __restrict__ emb_bf,
    const unsigned short* __restrict__ wc_bf,
    const float* __restrict__ bc,
    unsigned short* __restrict__ enc_bf)
{
    __shared__ unsigned short A_lds[128 * 128];   // [row][k] swizzled (32KB)
    __shared__ unsigned short B_lds[128 * 128];   // [col][k] swizzled (32KB)
    const int tid = threadIdx.x;
    const int blk = blockIdx.x;
    const int e = blk >> 10;
    const int tree0 = (blk & 1023) * 8;
    const int* __restrict__ tok = e ? tok2 : tok1;

    const int lane = tid & 63;
    const int tr  = tid >> 6;        // tree 0..7 (== wave)
    const int ng  = lane >> 4;       // node group: nodes ng*4..ng*4+3
    const int seg = lane & 15;       // 8-dim segment

    u32x4 wcv[4];
    #pragma unroll
    for (int it = 0; it < 4; ++it) {
        const int idx = tid + 512 * it;          // 0..2047
        wcv[it] = *(const u32x4*)(wc_bf + (idx >> 4) * EE + (idx & 15) * 8);
    }

    const int tb = (tree0 + tr) * KN + ng * 4;
    const int tk0 = tok[tb + 0], tk1 = tok[tb + 1], tk2 = tok[tb + 2], tk3 = tok[tb + 3];
    f32x8 a0 = cvt8(*(const bf8*)(emb_bf + (size_t)tk0 * EE + seg * 8));
    f32x8 a1 = cvt8(*(const bf8*)(emb_bf + (size_t)tk1 * EE + seg * 8));
    f32x8 a2 = cvt8(*(const bf8*)(emb_bf + (size_t)tk2 * EE + seg * 8));
    f32x8 a3 = cvt8(*(const bf8*)(emb_bf + (size_t)tk3 * EE + seg * 8));

    {
        f32x8 t0 = shx(a3, 32);
        if (ng == 1) a3 += t0;
        f32x8 u1 = shx(a3, 16), u2 = shx(a0, 32);
        if (ng == 0) a3 += u1 + u2;
        f32x8 v1 = shx(a1, 48), v2 = shx(a2, 48);
        if (ng == 1) a0 += v1 + v2;
        f32x8 w1 = shx(a3, 48), w2 = shx(a0, 32);
        if (ng == 1) a1 += w1 + w2;
        f32x8 x1 = shx(a1, 32), x2 = shx(a2, 32);
        if (ng == 1) a2 += x1 + x2;
        f32x8 z1 = shx(a0, 16);
        if (ng == 0) a1 += a3 + z1;
        f32x8 z2 = shx(a1, 16), z3 = shx(a2, 16);
        if (ng == 0) a2 += z2 + z3;
        if (ng == 0) a0 += a1 + a2;
    }

    {
        const int r0 = tr * 16 + ng * 4;
        *(bf8*)((char*)A_lds + (r0+0) * 256 + SWZ(r0+0, seg * 16)) = pack8(a0);
        *(bf8*)((char*)A_lds + (r0+1) * 256 + SWZ(r0+1, seg * 16)) = pack8(a1);
        *(bf8*)((char*)A_lds + (r0+2) * 256 + SWZ(r0+2, seg * 16)) = pack8(a2);
        *(bf8*)((char*)A_lds + (r0+3) * 256 + SWZ(r0+3, seg * 16)) = pack8(a3);
    }
    #pragma unroll
    for (int it = 0; it < 4; ++it) {
        const int idx = tid + 512 * it;
        const int row = idx >> 4, sg = idx & 15;
        *(u32x4*)((char*)B_lds + row * 256 + SWZ(row, sg * 16)) = wcv[it];
    }
    __syncthreads();

    const int wid = tid >> 6;
    const int wr = wid >> 1, wc = wid & 1;
    const int l15 = lane & 15, lg = lane >> 4;

    f32x4 acc[2][4];
    #pragma unroll
    for (int rt = 0; rt < 2; ++rt)
        #pragma unroll
        for (int ct = 0; ct < 4; ++ct) acc[rt][ct] = (f32x4){0.f, 0.f, 0.f, 0.f};

    #pragma unroll
    for (int ks = 0; ks < 4; ++ks) {
        bf8 aF[2], bF[4];
        #pragma unroll
        for (int rt = 0; rt < 2; ++rt) {
            const int row = wr * 32 + rt * 16 + l15;
            aF[rt] = *(const bf8*)((const char*)A_lds + row * 256 + SWZ(row, ks * 64 + lg * 16));
        }
        #pragma unroll
        for (int ct = 0; ct < 4; ++ct) {
            const int col = wc * 64 + ct * 16 + l15;
            bF[ct] = *(const bf8*)((const char*)B_lds + col * 256 + SWZ(col, ks * 64 + lg * 16));
        }
        #pragma unroll
        for (int rt = 0; rt < 2; ++rt)
            #pragma unroll
            for (int ct = 0; ct < 4; ++ct)
                acc[rt][ct] = __builtin_amdgcn_mfma_f32_16x16x32_bf16(aF[rt], bF[ct], acc[rt][ct], 0, 0, 0);
    }

    #pragma unroll
    for (int rt = 0; rt < 2; ++rt) {
        const int ltree = wr * 2 + rt;
        #pragma unroll
        for (int ct = 0; ct < 4; ++ct) {
            const int col = wc * 64 + ct * 16 + l15;
            const float bcv = bc[col];
            f32x4 v = acc[rt][ct];
            float m = -1e30f;
            #pragma unroll
            for (int r = 0; r < 4; ++r)
                m = fmaxf(m, v[r] + c_cnt[lg * 4 + r] * bcv);
            m = fmaxf(m, __shfl_xor(m, 16));
            m = fmaxf(m, __shfl_xor(m, 32));
            m = fmaxf(m, 0.f);
            if (lg == 0) {
                const int gtree = tree0 + ltree;
                const int row = (gtree & 127) * 64 + (gtree >> 7);   // t*64 + b
                enc_bf[((size_t)e * NTREE + row) * EE + col] = f2bf(m);
            }
        }
    }
}

// ---------------------------------------------------------------------------
// K3: fused GRU scan. 64 blocks (e, dir, bgroup-of-4) x 448 thr (7 waves).
// MFMA B uses 4 real seq columns (x4 duplicated). After MFMA each wave
// transposes its 64 real gate-units through wave-private LDS (no barrier)
// so every lane does exactly ONE gate-unit of VALU work.
// Biases folded into MFMA acc init. h stored per-seq 256B rows with
// chunk-rotation (k2+4c)&15 -> broadcast B-frag reads, conflict-free writes.
// Raw s_barrier + lgkmcnt only; enc prefetch (depth 2) floats across.
// ---------------------------------------------------------------------------
__global__ __launch_bounds__(448, 1) void k_gru(
    const unsigned short* __restrict__ enc_bf,
    const unsigned short* __restrict__ wih_pad,
    const unsigned short* __restrict__ whh_pad,
    const float* __restrict__ bih_f, const float* __restrict__ bih_b,
    const float* __restrict__ bhh_f, const float* __restrict__ bhh_b,
    float* __restrict__ hmax_out)
{
    __shared__ unsigned char h_lds[2][4 * 256];   // [buf][seq][chunk-rotated k] 2KB
    __shared__ float gate_scr[4][7][64];          // [gate][wave][slot] 7KB
    const int tid  = threadIdx.x;
    const int blk  = blockIdx.x;        // 64
    const int e    = blk >> 5;
    const int dir  = (blk >> 4) & 1;
    const int b0   = (blk & 15) * 4;
    const int w    = tid >> 6;
    const int lane = tid & 63;
    const int l15  = lane & 15;
    const int lg   = lane >> 4;
    const int c    = l15 & 3;           // seq column (x4 duplicated)
    const int jbase = w * 16;
    const int useq = lane >> 4 == 4 ? 3 : (lane >> 4);  // unit seq (lane>>4 is 0..3)
    const int uj   = jbase + (lane & 15);               // unit j

    for (int u = tid; u < 512; u += 448)
        ((unsigned int*)h_lds)[u] = 0u;

    // weight A-frags: row j = jbase + l15, k = ks*32 + lg*8
    bf8 aI[3][4], aH[3][4];
    {
        const unsigned short* wiP = wih_pad + (size_t)dir * 3 * 128 * 128;
        const unsigned short* whP = whh_pad + (size_t)dir * 3 * 128 * 128;
        #pragma unroll
        for (int g = 0; g < 3; ++g)
            #pragma unroll
            for (int ks = 0; ks < 4; ++ks) {
                const size_t ro = (size_t)(g * 128 + jbase + l15) * 128 + ks * 32 + lg * 8;
                aI[g][ks] = *(const bf8*)(wiP + ro);
                aH[g][ks] = *(const bf8*)(whP + ro);
                asm volatile("" : "+v"(aI[g][ks]));
                asm volatile("" : "+v"(aH[g][ks]));
            }
    }
    // biases folded into acc init: reg r <-> row j = jbase + lg*4 + r
    const float* __restrict__ bih = dir ? bih_b : bih_f;
    const float* __restrict__ bhh = dir ? bhh_b : bhh_f;
    f32x4 bR, bZ, bI_, bH_;
    #pragma unroll
    for (int r = 0; r < 4; ++r) {
        const int j = jbase + lg * 4 + r;
        bR[r]  = (j < 100) ? bih[j]       + bhh[j]       : 0.f;
        bZ[r]  = (j < 100) ? bih[100 + j] + bhh[100 + j] : 0.f;
        bI_[r] = (j < 100) ? bih[200 + j] : 0.f;
        bH_[r] = (j < 100) ? bhh[200 + j] : 0.f;
    }

    const unsigned short* encp =
        enc_bf + ((size_t)e * NTREE + b0 + c) * EE + lg * 8;

    // depth-2 prefetch of enc B-fragments
    bf8 eA[4], eB[4];
    {
        const int tm0 = dir ? 127 : 0;
        const int tm1 = dir ? 126 : 1;
        #pragma unroll
        for (int ks = 0; ks < 4; ++ks) {
            eA[ks] = *(const bf8*)(encp + (size_t)tm0 * 8192 + ks * 32);
            eB[ks] = *(const bf8*)(encp + (size_t)tm1 * 8192 + ks * 32);
        }
    }

    float h_cur = 0.f;
    float hmx   = -1e30f;
    const int hw_off = ((((uj >> 3) + 4 * useq) & 15) << 4) + (uj & 7) * 2 + useq * 256;
    __syncthreads();

#define L2E  1.4426950408889634f
#define GRU_STEP(EF, P, PT)                                                    \
    {                                                                          \
        bf8 hF[4];                                                             \
        const unsigned char* hb = h_lds[P] + c * 256;                          \
        _Pragma("unroll")                                                      \
        for (int ks = 0; ks < 4; ++ks)                                         \
            hF[ks] = *(const bf8*)(hb + (((ks * 4 + lg + 4 * c) & 15) << 4));  \
        f32x4 ar = bR, az = bZ, ai = bI_, ah = bH_;                            \
        _Pragma("unroll")                                                      \
        for (int ks = 0; ks < 4; ++ks) {                                       \
            ar = __builtin_amdgcn_mfma_f32_16x16x32_bf16(aI[0][ks], EF[ks], ar, 0, 0, 0); \
            az = __builtin_amdgcn_mfma_f32_16x16x32_bf16(aI[1][ks], EF[ks], az, 0, 0, 0); \
            ai = __builtin_amdgcn_mfma_f32_16x16x32_bf16(aI[2][ks], EF[ks], ai, 0, 0, 0); \
        }                                                                      \
        if ((PT) < S_) {                                                       \
            const int tmn = dir ? (127 - (PT)) : (PT);                         \
            _Pragma("unroll")                                                  \
            for (int ks = 0; ks < 4; ++ks)                                     \
                EF[ks] = *(const bf8*)(encp + (size_t)tmn * 8192 + ks * 32);   \
        }                                                                      \
        _Pragma("unroll")                                                      \
        for (int ks = 0; ks < 4; ++ks) {                                       \
            ar = __builtin_amdgcn_mfma_f32_16x16x32_bf16(aH[0][ks], hF[ks], ar, 0, 0, 0); \
            az = __builtin_amdgcn_mfma_f32_16x16x32_bf16(aH[1][ks], hF[ks], az, 0, 0, 0); \
            ah = __builtin_amdgcn_mfma_f32_16x16x32_bf16(aH[2][ks], hF[ks], ah, 0, 0, 0); \
        }                                                                      \
        if (l15 < 4) {                                                         \
            const int wo = l15 * 16 + lg * 4;                                  \
            *(f32x4*)&gate_scr[0][w][wo] = ar;                                 \
            *(f32x4*)&gate_scr[1][w][wo] = az;                                 \
            *(f32x4*)&gate_scr[2][w][wo] = ai;                                 \
            *(f32x4*)&gate_scr[3][w][wo] = ah;                                 \
        }                                                                      \
        asm volatile("s_waitcnt lgkmcnt(0)" ::: "memory");                     \
        {                                                                      \
            const float gr  = gate_scr[0][w][lane];                            \
            const float gz  = gate_scr[1][w][lane];                            \
            const float gi_ = gate_scr[2][w][lane];                            \
            const float gh_ = gate_scr[3][w][lane];                            \
            const float rg  = __builtin_amdgcn_rcpf(1.f + __builtin_amdgcn_exp2f(-L2E * gr)); \
            const float zg  = __builtin_amdgcn_rcpf(1.f + __builtin_amdgcn_exp2f(-L2E * gz)); \
            const float nx  = gi_ + rg * gh_;                                  \
            const float ng  = 1.f - 2.f * __builtin_amdgcn_rcpf(1.f + __builtin_amdgcn_exp2f((2.f * L2E) * nx)); \
            const float hnew = ng + zg * (h_cur - ng);                         \
            h_cur = hnew;                                                      \
            hmx = fmaxf(hmx, hnew);                                            \
            *(unsigned short*)(h_lds[(P) ^ 1] + hw_off) = f2bf(hnew);          \
        }                                                                      \
        asm volatile("s_waitcnt lgkmcnt(0)" ::: "memory");                     \
        __builtin_amdgcn_s_barrier();                                          \
        __builtin_amdgcn_sched_barrier(0);                                     \
    }

    for (int t = 0; t < S_; t += 2) {
        GRU_STEP(eA, 0, t + 2)
        GRU_STEP(eB, 1, t + 3)
    }
#undef GRU_STEP

    if (uj < 100)
        hmax_out[((size_t)((e * 2 + dir) * 64 + b0 + useq)) * HH + uj] = hmx;
}

// ---------------------------------------------------------------------------
// K4: fc + softmax
// ---------------------------------------------------------------------------
__global__ void k_final(const float* __restrict__ hmax,
                        const float* __restrict__ fcw,
                        const float* __restrict__ fcb,
                        float* __restrict__ out)
{
    const int b = threadIdx.x;
    if (b >= B_) return;
    float y0 = fcb[0], y1 = fcb[1];
    for (int m = 0; m < 400; ++m) {
        const int e   = m / 200;
        const int dm  = m % 200;
        const int dir = dm / 100;
        const int j   = dm % 100;
        const float x = hmax[((size_t)((e * 2 + dir) * 64 + b)) * HH + j];
        y0 += fcw[m]       * x;
        y1 += fcw[400 + m] * x;
    }
    const float mx = fmaxf(y0, y1);
    const float e0 = __expf(y0 - mx), e1 = __expf(y1 - mx);
    const float s = e0 + e1;
    out[b * 2]     = e0 / s;
    out[b * 2 + 1] = e1 / s;
}

extern "C" void kernel_launch(void* const* d_in, const int* in_sizes, int n_in,
                              void* d_out, int out_size, void* d_ws, size_t ws_size,
                              hipStream_t stream)
{
    const int*   tok1  = (const int*)d_in[0];
    const int*   tok2  = (const int*)d_in[1];
    const float* emb   = (const float*)d_in[4];
    const float* Wc    = (const float*)d_in[5];
    const float* bc    = (const float*)d_in[6];
    const float* wih_f = (const float*)d_in[7];
    const float* whh_f = (const float*)d_in[8];
    const float* bih_f = (const float*)d_in[9];
    const float* bhh_f = (const float*)d_in[10];
    const float* wih_b = (const float*)d_in[11];
    const float* whh_b = (const float*)d_in[12];
    const float* bih_b = (const float*)d_in[13];
    const float* bhh_b = (const float*)d_in[14];
    const float* fcw   = (const float*)d_in[15];
    const float* fcb   = (const float*)d_in[16];

    char* ws = (char*)d_ws;
    unsigned short* emb_bf  = (unsigned short*)(ws + EMB_BF_OFF);
    unsigned short* wc_bf   = (unsigned short*)(ws + WC_BF_OFF);
    unsigned short* wih_pad = (unsigned short*)(ws + WIH_BF_OFF);
    unsigned short* whh_pad = (unsigned short*)(ws + WHH_BF_OFF);
    unsigned short* enc_bf  = (unsigned short*)(ws + ENC_BF_OFF);
    float*          hmax    = (float*)(ws + HMAX_OFF);

    k_prep<<<6458, 256, 0, stream>>>(emb, Wc, wih_f, wih_b, whh_f, whh_b,
                                     emb_bf, wc_bf, wih_pad, whh_pad);
    k_encode<<<2048, 512, 0, stream>>>(tok1, tok2, emb_bf, wc_bf, bc, enc_bf);
    k_gru<<<64, 448, 0, stream>>>(enc_bf, wih_pad, whh_pad,
                                  bih_f, bih_b, bhh_f, bhh_b, hmax);
    k_final<<<1, 64, 0, stream>>>(hmax, fcw, fcb, (float*)d_out);
}